// Round 4
// baseline (775.990 us; speedup 1.0000x reference)
//
#include <hip/hip_runtime.h>
#include <hip/hip_bf16.h>
#include <math.h>

// Problem constants
#define B 32
#define N 128
#define BT (B*N)          // 4096
#define WD 100
#define UD 25
#define D 125             // LSTM hidden per direction
#define G4 (4*D)          // 500 gates
#define H2 (2*D)          // 250
#define HID 100
#define L 50

// Fast, overflow-safe activations on v_exp_f32
__device__ __forceinline__ float fast_tanh(float x) {
    float e = __expf(2.0f * x);
    return 1.0f - 2.0f / (e + 1.0f);
}
__device__ __forceinline__ float fast_sigmoid(float x) {
    return 1.0f / (1.0f + __expf(-x));
}
__device__ __forceinline__ float bcast_lane(float v, int k) {
    return __builtin_bit_cast(float, __builtin_amdgcn_readlane(__builtin_bit_cast(int, v), k));
}

// ---------------------------------------------------------------------------
// K0a: combined-bias setup (b_l0[1000], b_l1[1000], b_s3[300])
// ---------------------------------------------------------------------------
__global__ void bias_setup(const float* __restrict__ l0f_b, const float* __restrict__ l0b_b,
                           const float* __restrict__ l1f_b, const float* __restrict__ l1b_b,
                           const float* __restrict__ eh_b, const float* __restrict__ em_b,
                           const float* __restrict__ lm_b,
                           float* __restrict__ b_l0, float* __restrict__ b_l1,
                           float* __restrict__ b_s3) {
    int t = blockIdx.x * blockDim.x + threadIdx.x;
    if (t < 500)        b_l0[t] = l0f_b[t];
    else if (t < 1000)  b_l0[t] = l0b_b[t-500];
    else if (t < 1500)  b_l1[t-1000] = l1f_b[t-1000];
    else if (t < 2000)  b_l1[t-1000] = l1b_b[t-1500];
    else if (t < 2100)  b_s3[t-2000] = eh_b[t-2000];
    else if (t < 2200)  b_s3[t-2000] = em_b[t-2100];
    else if (t < 2300)  b_s3[t-2000] = lm_b[t-2200];
}

// ---------------------------------------------------------------------------
// K0b: fused LDS-tiled transpose. out[k*ldo + coff + n] = in[n*C + k].
//      One launch covers all 12 weight matrices; coalesced on both sides.
// ---------------------------------------------------------------------------
struct TJob { const float* src; float* dst; int R, C, ldo, coff, tile0, tiles_x; };
struct TArgs { TJob j[12]; };

__global__ __launch_bounds__(256)
void transpose_fused(TArgs a) {
    int bid = blockIdx.x;
    int ji = 0;
    #pragma unroll
    for (int i = 1; i < 12; i++) if (bid >= a.j[i].tile0) ji = i;
    TJob jb = a.j[ji];
    int t = bid - jb.tile0;
    int tx = t % jb.tiles_x;        // tile along C (k)
    int ty = t / jb.tiles_x;        // tile along R (n)
    __shared__ float tile[32][33];
    int k0 = tx*32, n0 = ty*32;
    #pragma unroll
    for (int dy = 0; dy < 32; dy += 8) {
        int n = n0 + threadIdx.y + dy;
        int k = k0 + threadIdx.x;
        if (n < jb.R && k < jb.C)
            tile[threadIdx.y+dy][threadIdx.x] = jb.src[(size_t)n*jb.C + k];
    }
    __syncthreads();
    #pragma unroll
    for (int dy = 0; dy < 32; dy += 8) {
        int k = k0 + threadIdx.y + dy;
        int n = n0 + threadIdx.x;
        if (k < jb.C && n < jb.R)
            jb.dst[(size_t)k*jb.ldo + jb.coff + n] = tile[threadIdx.x][threadIdx.y+dy];
    }
}

// ---------------------------------------------------------------------------
// K1: embedding gather
// ---------------------------------------------------------------------------
__global__ void embed_kernel(const int* __restrict__ wids, const int* __restrict__ uids,
                             const float* __restrict__ wl, const float* __restrict__ tl,
                             float* __restrict__ words) {
    int bt = blockIdx.x;
    int t = threadIdx.x;           // 128 threads
    int wid = wids[bt];
    int uid = uids[bt];
    if (t < WD)       words[bt*D + t] = wl[wid*WD + t];
    else if (t < D)   words[bt*D + t] = tl[uid*UD + (t - WD)];
}

// ---------------------------------------------------------------------------
// K2: projection GEMM, transposed weights, CPT columns per thread.
//     out[m][n] = sum_k x[row(m)][k] * WT[k][n] + bias[n]
//     Each readlane broadcast feeds CPT FMAs (1.5 instr/MAC at CPT=2).
// ---------------------------------------------------------------------------
#define MT 16
template<int CPT>
__global__ __launch_bounds__(512)
void proj_t(const float* __restrict__ x, const float* __restrict__ WT,
            const float* __restrict__ bias, float* __restrict__ out,
            int Ncols, int K, int ldx, const int* __restrict__ gather_idx) {
    __shared__ float xs[250 * 17 + 16];   // xs[k*17 + r]
    int m0 = blockIdx.x * MT;
    for (int r = 0; r < MT; r++) {
        int m = m0 + r;
        int row = m;
        if (gather_idx) {
            int bb = m >> 7, np = m & 127;
            row = (bb << 7) + (np == 0 ? 0 : gather_idx[m]);
        }
        for (int k = threadIdx.x; k < K; k += blockDim.x)
            xs[k*17 + r] = x[(size_t)row*ldx + k];
    }
    __syncthreads();
    int n0 = threadIdx.x;
    int lane = threadIdx.x & 63;
    int bd = blockDim.x;
    float acc[CPT][MT];
    int ncl[CPT];
    #pragma unroll
    for (int j = 0; j < CPT; j++) {
        int n = n0 + j*bd;
        ncl[j] = (n < Ncols) ? n : (Ncols - 1);
        #pragma unroll
        for (int r = 0; r < MT; r++) acc[j][r] = 0.0f;
    }
    int k0 = 0;
    for (; k0 + 4 <= K; k0 += 4) {
        float xv = xs[(k0 + (lane >> 4))*17 + (lane & 15)];
        float wk[4][CPT];
        #pragma unroll
        for (int q = 0; q < 4; q++)
            #pragma unroll
            for (int j = 0; j < CPT; j++)
                wk[q][j] = WT[(size_t)(k0 + q)*Ncols + ncl[j]];
        #pragma unroll
        for (int q = 0; q < 4; q++) {
            #pragma unroll
            for (int r = 0; r < 16; r++) {
                float hv = bcast_lane(xv, q*16 + r);
                #pragma unroll
                for (int j = 0; j < CPT; j++)
                    acc[j][r] = fmaf(wk[q][j], hv, acc[j][r]);
            }
        }
    }
    for (; k0 < K; k0++) {                 // tail (K=125 -> 1, K=250 -> 2)
        float xv = xs[k0*17 + (lane & 15)];
        float wk[CPT];
        #pragma unroll
        for (int j = 0; j < CPT; j++) wk[j] = WT[(size_t)k0*Ncols + ncl[j]];
        #pragma unroll
        for (int r = 0; r < 16; r++) {
            float hv = bcast_lane(xv, r);
            #pragma unroll
            for (int j = 0; j < CPT; j++)
                acc[j][r] = fmaf(wk[j], hv, acc[j][r]);
        }
    }
    #pragma unroll
    for (int j = 0; j < CPT; j++) {
        int n = n0 + j*bd;
        if (n < Ncols) {
            float bb = bias[n];
            #pragma unroll
            for (int r = 0; r < MT; r++) out[(size_t)(m0 + r)*Ncols + n] = acc[j][r] + bb;
        }
    }
}

// ---------------------------------------------------------------------------
// K3: LSTM scan. One block per (batch, direction); 512 threads.
//     Whh is pre-transposed [125][500] so the preload is coalesced.
//     volatile loads (non-sinkable) + asm pins + 256-VGPR budget keep the
//     125 weights register-resident across the 128-step loop.
// ---------------------------------------------------------------------------
__global__ __launch_bounds__(512, 2)
void lstm_scan(const float* __restrict__ xgc,
               const float* __restrict__ WhTf, const float* __restrict__ WhTb,
               float* __restrict__ out) {
    int dir = blockIdx.x & 1;
    int b = blockIdx.x >> 1;
    const float* WhT = dir ? WhTb : WhTf;   // [125][500]
    int off = dir ? D : 0;
    int g = threadIdx.x;
    int lane = g & 63;
    bool active = (g < G4);
    int gc = active ? g : (G4 - 1);

    __shared__ float hbuf[128];
    __shared__ float gbuf[G4];

    float w[125];
    {
        const volatile float* wt = WhT;     // volatile: loads can't be sunk/remat'd
        #pragma unroll
        for (int k = 0; k < 125; k++) w[k] = wt[(size_t)k*G4 + gc];
    }
    #pragma unroll
    for (int k = 0; k < 125; k++) asm volatile("" : "+v"(w[k]));

    float c = 0.0f;
    if (g < 128) hbuf[g] = 0.0f;
    __syncthreads();

    const float* xb = xgc + (size_t)b * N * 1000 + dir * 500;
    float x_next = active ? xb[(size_t)(dir ? (N-1) : 0) * 1000 + g] : 0.0f;

    for (int t = 0; t < N; t++) {
        int tt = dir ? (N-1-t) : t;
        float x_cur = x_next;
        float xn = 0.0f;
        if (active && t + 1 < N)
            xn = xb[(size_t)(dir ? (tt-1) : (tt+1)) * 1000 + g];
        float h0v = hbuf[lane];
        float h1v = hbuf[64 + lane];
        float a0 = x_cur, a1 = 0.0f, a2 = 0.0f, a3 = 0.0f;
        #pragma unroll
        for (int k = 0; k < 64; k += 4) {
            a0 = fmaf(w[k],   bcast_lane(h0v, k),   a0);
            a1 = fmaf(w[k+1], bcast_lane(h0v, k+1), a1);
            a2 = fmaf(w[k+2], bcast_lane(h0v, k+2), a2);
            a3 = fmaf(w[k+3], bcast_lane(h0v, k+3), a3);
        }
        #pragma unroll
        for (int k = 0; k < 60; k += 4) {
            a0 = fmaf(w[64+k],   bcast_lane(h1v, k),   a0);
            a1 = fmaf(w[64+k+1], bcast_lane(h1v, k+1), a1);
            a2 = fmaf(w[64+k+2], bcast_lane(h1v, k+2), a2);
            a3 = fmaf(w[64+k+3], bcast_lane(h1v, k+3), a3);
        }
        a0 = fmaf(w[124], bcast_lane(h1v, 60), a0);
        x_next = xn;
        if (active) gbuf[g] = (a0 + a1) + (a2 + a3);
        __syncthreads();
        if (g < D) {
            float iv = gbuf[g], fv = gbuf[D+g], gv = gbuf[2*D+g], ov = gbuf[3*D+g];
            float si = fast_sigmoid(iv);
            float sf = fast_sigmoid(fv);
            float so = fast_sigmoid(ov);
            c = sf * c + si * fast_tanh(gv);
            float h = so * fast_tanh(c);
            hbuf[g] = h;
            out[(size_t)(b*N + tt)*H2 + off + g] = h;
        }
        __syncthreads();
    }
}

// ---------------------------------------------------------------------------
// K4: arc scores + margin + argmax. Block per (b, 4-i tile); 128 threads (j).
//     wh/wm live in the fused s3 buffer [m][300]: wh at +0, wm at +100.
// ---------------------------------------------------------------------------
#define ITILE 4
__global__ __launch_bounds__(128)
void arc_kernel(const float* __restrict__ s3,
                const float* __restrict__ esW, const float* __restrict__ esb,
                const int* __restrict__ ta,
                float* __restrict__ arc_out, float* __restrict__ tree_out) {
    int blk = blockIdx.x;             // b*32 + it
    int b = blk >> 5, it = blk & 31;
    int j = threadIdx.x;              // 128 threads

    __shared__ float wms[128 * 101];
    __shared__ float whs[ITILE][HID];
    __shared__ float es[HID];
    __shared__ float sv[128];
    __shared__ int   si[128];

    for (int e = j; e < 128 * HID; e += 128) {
        int r = e / HID, h = e - r * HID;
        wms[r*101 + h] = s3[(size_t)(b*N + r)*300 + 100 + h];
    }
    for (int e = j; e < ITILE * HID; e += 128) {
        int ii = e / HID, h = e - ii * HID;
        whs[ii][h] = s3[(size_t)(b*N + it*ITILE + ii)*300 + h];
    }
    if (j < HID) es[j] = esW[j];
    __syncthreads();

    float eb = esb[0];
    const float* wmr = &wms[j * 101];
    for (int ii = 0; ii < ITILE; ii++) {
        int i = it * ITILE + ii;
        int bi = b * N + i;
        float acc = 0.0f;
        for (int h = 0; h < HID; h++)
            acc = fmaf(es[h], fast_tanh(whs[ii][h] + wmr[h]), acc);
        int tai = (i == 0) ? 0 : ta[bi];
        float score = acc + eb + 1.0f - ((j == tai) ? 1.0f : 0.0f);
        arc_out[(size_t)bi*N + j] = score;
        sv[j] = score; si[j] = j;
        __syncthreads();
        for (int s = 64; s; s >>= 1) {
            if (j < s) {
                float ov = sv[j+s]; int oi = si[j+s];
                if (ov > sv[j] || (ov == sv[j] && oi < si[j])) { sv[j] = ov; si[j] = oi; }
            }
            __syncthreads();
        }
        if (j == 0) tree_out[bi] = (float)si[0];
        __syncthreads();
    }
}

// ---------------------------------------------------------------------------
// K5: rel scores + argmax. One block (64 threads) per bt.
//     rel_mod at s3[m][200..300); rel_head separate [m][100].
// ---------------------------------------------------------------------------
__global__ void rel_kernel(const float* __restrict__ s3, const float* __restrict__ rh,
                           const float* __restrict__ lsW, const float* __restrict__ lsb,
                           float* __restrict__ rel_out, float* __restrict__ pred_out) {
    int bt = blockIdx.x;
    int t = threadIdx.x;          // 64 threads

    __shared__ float tv[HID];
    __shared__ float sv[64];
    __shared__ int   si[64];

    for (int h = t; h < HID; h += 64)
        tv[h] = fast_tanh(s3[(size_t)bt*300 + 200 + h] + rh[(size_t)bt*HID + h]);
    __syncthreads();

    float score = -1e30f;
    if (t < L) {
        float acc = 0.0f;
        const float* wrow = lsW + t*HID;
        for (int h = 0; h < HID; h++) acc = fmaf(wrow[h], tv[h], acc);
        score = acc + lsb[t];
        rel_out[(size_t)bt*L + t] = score;
    }
    sv[t] = score;
    si[t] = t;
    __syncthreads();
    for (int s = 32; s; s >>= 1) {
        if (t < s) {
            float ov = sv[t + s]; int oi = si[t + s];
            if (ov > sv[t] || (ov == sv[t] && oi < si[t])) { sv[t] = ov; si[t] = oi; }
        }
        __syncthreads();
    }
    if (t == 0) pred_out[bt] = (float)si[0];
}

// ---------------------------------------------------------------------------
extern "C" void kernel_launch(void* const* d_in, const int* in_sizes, int n_in,
                              void* d_out, int out_size, void* d_ws, size_t ws_size,
                              hipStream_t stream) {
    const int*   word_ids    = (const int*)  d_in[0];
    const int*   upos_ids    = (const int*)  d_in[1];
    const int*   target_arcs = (const int*)  d_in[2];
    const float* wlookup     = (const float*)d_in[3];
    const float* tlookup     = (const float*)d_in[4];
    const float* l0f_Wih = (const float*)d_in[5];
    const float* l0f_Whh = (const float*)d_in[6];
    const float* l0f_b   = (const float*)d_in[7];
    const float* l0b_Wih = (const float*)d_in[8];
    const float* l0b_Whh = (const float*)d_in[9];
    const float* l0b_b   = (const float*)d_in[10];
    const float* l1f_Wih = (const float*)d_in[11];
    const float* l1f_Whh = (const float*)d_in[12];
    const float* l1f_b   = (const float*)d_in[13];
    const float* l1b_Wih = (const float*)d_in[14];
    const float* l1b_Whh = (const float*)d_in[15];
    const float* l1b_b   = (const float*)d_in[16];
    const float* eh_W = (const float*)d_in[17];
    const float* eh_b = (const float*)d_in[18];
    const float* em_W = (const float*)d_in[19];
    const float* em_b = (const float*)d_in[20];
    const float* es_W = (const float*)d_in[21];
    const float* es_b = (const float*)d_in[22];
    const float* lh_W = (const float*)d_in[23];
    const float* lh_b = (const float*)d_in[24];
    const float* lm_W = (const float*)d_in[25];
    const float* lm_b = (const float*)d_in[26];
    const float* ls_W = (const float*)d_in[27];
    const float* ls_b = (const float*)d_in[28];

    float* out = (float*)d_out;
    float* trees_out = out;                         // 4096
    float* preds_out = out + BT;                    // 4096
    float* arc_out   = out + 2*BT;                  // 524288
    float* rel_out   = out + 2*BT + BT*N;           // 204800

    float* ws = (float*)d_ws;
    float* A       = ws;                    // 4,096,000: xg fused [m][1000]; later s3 [m][300]
    float* words   = ws + 4096000;          //   512,000
    float* C       = ws + 4608000;          // 1,024,000: h0, then ex
    float* WT_l0   = ws + 5632000;          //   125,000  [125][1000]
    float* WT_l1   = ws + 5757000;          //   250,000  [250][1000]
    float* WT_s3   = ws + 6007000;          //    75,000  [250][300]
    float* WT_lh   = ws + 6082000;          //    25,000  [250][100]
    float* WhT_l0f = ws + 6107000;          //    62,500  [125][500]
    float* WhT_l0b = ws + 6169500;          //    62,500
    float* WhT_l1f = ws + 6232000;          //    62,500
    float* WhT_l1b = ws + 6294500;          //    62,500
    float* b_l0    = ws + 6357000;          //     1,000
    float* b_l1    = ws + 6358000;          //     1,000
    float* b_s3    = ws + 6359000;          //     1,000 (300 used)
    float* rel_head = ws + 6360000;         //   409,600  [m][100]
    // total 6,769,600 floats = 27.1 MB

    // 0. fused biases + one fused tiled transpose for all 12 weight matrices
    bias_setup<<<9, 256, 0, stream>>>(l0f_b, l0b_b, l1f_b, l1b_b, eh_b, em_b, lm_b,
                                      b_l0, b_l1, b_s3);
    {
        TArgs ta{};
        auto tiles = [](int R, int C_) { return ((C_+31)/32) * ((R+31)/32); };
        struct { const float* s; float* d; int R, C, ldo, coff; } js[12] = {
            { l0f_Wih, WT_l0, 500, 125, 1000, 0 },
            { l0b_Wih, WT_l0, 500, 125, 1000, 500 },
            { l1f_Wih, WT_l1, 500, 250, 1000, 0 },
            { l1b_Wih, WT_l1, 500, 250, 1000, 500 },
            { eh_W, WT_s3, 100, 250, 300, 0 },
            { em_W, WT_s3, 100, 250, 300, 100 },
            { lm_W, WT_s3, 100, 250, 300, 200 },
            { lh_W, WT_lh, 100, 250, 100, 0 },
            { l0f_Whh, WhT_l0f, 500, 125, 500, 0 },
            { l0b_Whh, WhT_l0b, 500, 125, 500, 0 },
            { l1f_Whh, WhT_l1f, 500, 125, 500, 0 },
            { l1b_Whh, WhT_l1b, 500, 125, 500, 0 },
        };
        int t0 = 0;
        for (int i = 0; i < 12; i++) {
            ta.j[i].src = js[i].s;  ta.j[i].dst = js[i].d;
            ta.j[i].R = js[i].R;    ta.j[i].C = js[i].C;
            ta.j[i].ldo = js[i].ldo; ta.j[i].coff = js[i].coff;
            ta.j[i].tile0 = t0;
            ta.j[i].tiles_x = (js[i].C + 31) / 32;
            t0 += tiles(js[i].R, js[i].C);
        }
        transpose_fused<<<t0, dim3(32, 8), 0, stream>>>(ta);
    }

    // 1. embeddings
    embed_kernel<<<BT, 128, 0, stream>>>(word_ids, upos_ids, wlookup, tlookup, words);

    // 2. layer-0 input projections, fused fwd+bwd (K=125, N=1000)
    proj_t<2><<<BT/MT, 512, 0, stream>>>(words, WT_l0, b_l0, A, 1000, D, D, nullptr);

    // 3. layer-0 scan -> h0 (C)
    lstm_scan<<<B*2, 512, 0, stream>>>(A, WhT_l0f, WhT_l0b, C);

    // 4. layer-1 input projections (K=250, N=1000)
    proj_t<2><<<BT/MT, 512, 0, stream>>>(C, WT_l1, b_l1, A, 1000, H2, H2, nullptr);

    // 5. layer-1 scan -> ex (C, overwrites h0)
    lstm_scan<<<B*2, 512, 0, stream>>>(A, WhT_l1f, WhT_l1b, C);

    // 6. scorer projections: eh+em+lm fused (N=300) into A; lh gathered (N=100)
    proj_t<2><<<BT/MT, 192, 0, stream>>>(C, WT_s3, b_s3, A, 300, H2, H2, nullptr);
    proj_t<1><<<BT/MT, 128, 0, stream>>>(C, WT_lh, lh_b, rel_head, 100, H2, H2, target_arcs);

    // 7. arc scores + margin + argmax
    arc_kernel<<<BT/ITILE, 128, 0, stream>>>(A, es_W, es_b, target_arcs,
                                             arc_out, trees_out);

    // 8. rel scores + argmax
    rel_kernel<<<BT, 64, 0, stream>>>(A, rel_head, ls_W, ls_b, rel_out, preds_out);
}

// Round 5
// 734.777 us; speedup vs baseline: 1.0561x; 1.0561x over previous
//
#include <hip/hip_runtime.h>
#include <hip/hip_bf16.h>
#include <math.h>

// Problem constants
#define B 32
#define N 128
#define BT (B*N)          // 4096
#define WD 100
#define UD 25
#define D 125             // LSTM hidden per direction
#define G4 (4*D)          // 500 gates
#define H2 (2*D)          // 250
#define HID 100
#define L 50

// Fast, overflow-safe activations on v_exp_f32
__device__ __forceinline__ float fast_tanh(float x) {
    float e = __expf(2.0f * x);
    return 1.0f - 2.0f / (e + 1.0f);
}
__device__ __forceinline__ float fast_sigmoid(float x) {
    return 1.0f / (1.0f + __expf(-x));
}
__device__ __forceinline__ float bcast_lane(float v, int k) {
    return __builtin_bit_cast(float, __builtin_amdgcn_readlane(__builtin_bit_cast(int, v), k));
}

// 125-way macro repetition (named scalars defeat the scratch-alloca problem:
// rounds 2-4 all showed VGPR_Count=76 => float w[125] lived in scratch).
#define REP125(X) \
 X(0) X(1) X(2) X(3) X(4) X(5) X(6) X(7) X(8) X(9) \
 X(10) X(11) X(12) X(13) X(14) X(15) X(16) X(17) X(18) X(19) \
 X(20) X(21) X(22) X(23) X(24) X(25) X(26) X(27) X(28) X(29) \
 X(30) X(31) X(32) X(33) X(34) X(35) X(36) X(37) X(38) X(39) \
 X(40) X(41) X(42) X(43) X(44) X(45) X(46) X(47) X(48) X(49) \
 X(50) X(51) X(52) X(53) X(54) X(55) X(56) X(57) X(58) X(59) \
 X(60) X(61) X(62) X(63) X(64) X(65) X(66) X(67) X(68) X(69) \
 X(70) X(71) X(72) X(73) X(74) X(75) X(76) X(77) X(78) X(79) \
 X(80) X(81) X(82) X(83) X(84) X(85) X(86) X(87) X(88) X(89) \
 X(90) X(91) X(92) X(93) X(94) X(95) X(96) X(97) X(98) X(99) \
 X(100) X(101) X(102) X(103) X(104) X(105) X(106) X(107) X(108) X(109) \
 X(110) X(111) X(112) X(113) X(114) X(115) X(116) X(117) X(118) X(119) \
 X(120) X(121) X(122) X(123) X(124)

// ---------------------------------------------------------------------------
// K0a: combined-bias setup (b_l0[1000], b_l1[1000], b_s3[300])
// ---------------------------------------------------------------------------
__global__ void bias_setup(const float* __restrict__ l0f_b, const float* __restrict__ l0b_b,
                           const float* __restrict__ l1f_b, const float* __restrict__ l1b_b,
                           const float* __restrict__ eh_b, const float* __restrict__ em_b,
                           const float* __restrict__ lm_b,
                           float* __restrict__ b_l0, float* __restrict__ b_l1,
                           float* __restrict__ b_s3) {
    int t = blockIdx.x * blockDim.x + threadIdx.x;
    if (t < 500)        b_l0[t] = l0f_b[t];
    else if (t < 1000)  b_l0[t] = l0b_b[t-500];
    else if (t < 1500)  b_l1[t-1000] = l1f_b[t-1000];
    else if (t < 2000)  b_l1[t-1000] = l1b_b[t-1500];
    else if (t < 2100)  b_s3[t-2000] = eh_b[t-2000];
    else if (t < 2200)  b_s3[t-2000] = em_b[t-2100];
    else if (t < 2300)  b_s3[t-2000] = lm_b[t-2200];
}

// ---------------------------------------------------------------------------
// K0b: fused LDS-tiled transpose. out[k*ldo + coff + n] = in[n*C + k].
// ---------------------------------------------------------------------------
struct TJob { const float* src; float* dst; int R, C, ldo, coff, tile0, tiles_x; };
struct TArgs { TJob j[12]; };

__global__ __launch_bounds__(256)
void transpose_fused(TArgs a) {
    int bid = blockIdx.x;
    int ji = 0;
    #pragma unroll
    for (int i = 1; i < 12; i++) if (bid >= a.j[i].tile0) ji = i;
    TJob jb = a.j[ji];
    int t = bid - jb.tile0;
    int tx = t % jb.tiles_x;        // tile along C (k)
    int ty = t / jb.tiles_x;        // tile along R (n)
    __shared__ float tile[32][33];
    int k0 = tx*32, n0 = ty*32;
    #pragma unroll
    for (int dy = 0; dy < 32; dy += 8) {
        int n = n0 + threadIdx.y + dy;
        int k = k0 + threadIdx.x;
        if (n < jb.R && k < jb.C)
            tile[threadIdx.y+dy][threadIdx.x] = jb.src[(size_t)n*jb.C + k];
    }
    __syncthreads();
    #pragma unroll
    for (int dy = 0; dy < 32; dy += 8) {
        int k = k0 + threadIdx.y + dy;
        int n = n0 + threadIdx.x;
        if (k < jb.C && n < jb.R)
            jb.dst[(size_t)k*jb.ldo + jb.coff + n] = tile[threadIdx.x][threadIdx.y+dy];
    }
}

// ---------------------------------------------------------------------------
// K1: embedding gather
// ---------------------------------------------------------------------------
__global__ void embed_kernel(const int* __restrict__ wids, const int* __restrict__ uids,
                             const float* __restrict__ wl, const float* __restrict__ tl,
                             float* __restrict__ words) {
    int bt = blockIdx.x;
    int t = threadIdx.x;           // 128 threads
    int wid = wids[bt];
    int uid = uids[bt];
    if (t < WD)       words[bt*D + t] = wl[wid*WD + t];
    else if (t < D)   words[bt*D + t] = tl[uid*UD + (t - WD)];
}

// ---------------------------------------------------------------------------
// K2: projection GEMM, transposed weights, CPT columns per thread.
// ---------------------------------------------------------------------------
#define MT 16
template<int CPT>
__global__ __launch_bounds__(512)
void proj_t(const float* __restrict__ x, const float* __restrict__ WT,
            const float* __restrict__ bias, float* __restrict__ out,
            int Ncols, int K, int ldx, const int* __restrict__ gather_idx) {
    __shared__ float xs[250 * 17 + 16];   // xs[k*17 + r]
    int m0 = blockIdx.x * MT;
    for (int r = 0; r < MT; r++) {
        int m = m0 + r;
        int row = m;
        if (gather_idx) {
            int bb = m >> 7, np = m & 127;
            row = (bb << 7) + (np == 0 ? 0 : gather_idx[m]);
        }
        for (int k = threadIdx.x; k < K; k += blockDim.x)
            xs[k*17 + r] = x[(size_t)row*ldx + k];
    }
    __syncthreads();
    int n0 = threadIdx.x;
    int lane = threadIdx.x & 63;
    int bd = blockDim.x;
    float acc[CPT][MT];
    int ncl[CPT];
    #pragma unroll
    for (int j = 0; j < CPT; j++) {
        int n = n0 + j*bd;
        ncl[j] = (n < Ncols) ? n : (Ncols - 1);
        #pragma unroll
        for (int r = 0; r < MT; r++) acc[j][r] = 0.0f;
    }
    int k0 = 0;
    for (; k0 + 4 <= K; k0 += 4) {
        float xv = xs[(k0 + (lane >> 4))*17 + (lane & 15)];
        float wk[4][CPT];
        #pragma unroll
        for (int q = 0; q < 4; q++)
            #pragma unroll
            for (int j = 0; j < CPT; j++)
                wk[q][j] = WT[(size_t)(k0 + q)*Ncols + ncl[j]];
        #pragma unroll
        for (int q = 0; q < 4; q++) {
            #pragma unroll
            for (int r = 0; r < 16; r++) {
                float hv = bcast_lane(xv, q*16 + r);
                #pragma unroll
                for (int j = 0; j < CPT; j++)
                    acc[j][r] = fmaf(wk[q][j], hv, acc[j][r]);
            }
        }
    }
    for (; k0 < K; k0++) {                 // tail (K=125 -> 1, K=250 -> 2)
        float xv = xs[k0*17 + (lane & 15)];
        float wk[CPT];
        #pragma unroll
        for (int j = 0; j < CPT; j++) wk[j] = WT[(size_t)k0*Ncols + ncl[j]];
        #pragma unroll
        for (int r = 0; r < 16; r++) {
            float hv = bcast_lane(xv, r);
            #pragma unroll
            for (int j = 0; j < CPT; j++)
                acc[j][r] = fmaf(wk[j], hv, acc[j][r]);
        }
    }
    #pragma unroll
    for (int j = 0; j < CPT; j++) {
        int n = n0 + j*bd;
        if (n < Ncols) {
            float bb = bias[n];
            #pragma unroll
            for (int r = 0; r < MT; r++) out[(size_t)(m0 + r)*Ncols + n] = acc[j][r] + bb;
        }
    }
}

// ---------------------------------------------------------------------------
// K3: LSTM scan. One block per (batch, direction); 512 threads.
//     Whh pre-transposed [125][500] (coalesced preload). Weights held in 125
//     NAMED scalar VGPRs (no alloca -> no scratch). h broadcast via readlane.
// ---------------------------------------------------------------------------
__global__ __launch_bounds__(512, 2)
void lstm_scan(const float* __restrict__ xgc,
               const float* __restrict__ WhTf, const float* __restrict__ WhTb,
               float* __restrict__ out) {
    int dir = blockIdx.x & 1;
    int b = blockIdx.x >> 1;
    const float* WhT = dir ? WhTb : WhTf;   // [125][500]
    int off = dir ? D : 0;
    int g = threadIdx.x;
    int lane = g & 63;
    bool active = (g < G4);
    int gc = active ? g : (G4 - 1);

    __shared__ float hbuf[128];
    __shared__ float gbuf[G4];

#define DECLW(i) float w##i = WhT[(size_t)(i)*G4 + gc];
    REP125(DECLW)
#undef DECLW

    float c = 0.0f;
    if (g < 128) hbuf[g] = 0.0f;
    __syncthreads();

    const float* xb = xgc + (size_t)b * N * 1000 + dir * 500;
    float x_next = active ? xb[(size_t)(dir ? (N-1) : 0) * 1000 + g] : 0.0f;

    for (int t = 0; t < N; t++) {
        int tt = dir ? (N-1-t) : t;
        float x_cur = x_next;
        float xn = 0.0f;
        if (active && t + 1 < N)
            xn = xb[(size_t)(dir ? (tt-1) : (tt+1)) * 1000 + g];
        float h0v = hbuf[lane];
        float h1v = hbuf[64 + lane];
        float a4[4];
        a4[0] = x_cur; a4[1] = 0.0f; a4[2] = 0.0f; a4[3] = 0.0f;
#define FMAW(i) a4[(i)&3] = fmaf(w##i, bcast_lane(((i) < 64) ? h0v : h1v, (i)&63), a4[(i)&3]);
        REP125(FMAW)
#undef FMAW
        x_next = xn;
        if (active) gbuf[g] = (a4[0] + a4[1]) + (a4[2] + a4[3]);
        __syncthreads();
        if (g < D) {
            float iv = gbuf[g], fv = gbuf[D+g], gv = gbuf[2*D+g], ov = gbuf[3*D+g];
            float si = fast_sigmoid(iv);
            float sf = fast_sigmoid(fv);
            float so = fast_sigmoid(ov);
            c = sf * c + si * fast_tanh(gv);
            float h = so * fast_tanh(c);
            hbuf[g] = h;
            out[(size_t)(b*N + tt)*H2 + off + g] = h;
        }
        __syncthreads();
    }
}

// ---------------------------------------------------------------------------
// K4: arc scores + margin + argmax. Block per (b, 4-i tile); 128 threads (j).
// ---------------------------------------------------------------------------
#define ITILE 4
__global__ __launch_bounds__(128)
void arc_kernel(const float* __restrict__ s3,
                const float* __restrict__ esW, const float* __restrict__ esb,
                const int* __restrict__ ta,
                float* __restrict__ arc_out, float* __restrict__ tree_out) {
    int blk = blockIdx.x;             // b*32 + it
    int b = blk >> 5, it = blk & 31;
    int j = threadIdx.x;              // 128 threads

    __shared__ float wms[128 * 101];
    __shared__ float whs[ITILE][HID];
    __shared__ float es[HID];
    __shared__ float sv[128];
    __shared__ int   si[128];

    for (int e = j; e < 128 * HID; e += 128) {
        int r = e / HID, h = e - r * HID;
        wms[r*101 + h] = s3[(size_t)(b*N + r)*300 + 100 + h];
    }
    for (int e = j; e < ITILE * HID; e += 128) {
        int ii = e / HID, h = e - ii * HID;
        whs[ii][h] = s3[(size_t)(b*N + it*ITILE + ii)*300 + h];
    }
    if (j < HID) es[j] = esW[j];
    __syncthreads();

    float eb = esb[0];
    const float* wmr = &wms[j * 101];
    for (int ii = 0; ii < ITILE; ii++) {
        int i = it * ITILE + ii;
        int bi = b * N + i;
        float acc = 0.0f;
        for (int h = 0; h < HID; h++)
            acc = fmaf(es[h], fast_tanh(whs[ii][h] + wmr[h]), acc);
        int tai = (i == 0) ? 0 : ta[bi];
        float score = acc + eb + 1.0f - ((j == tai) ? 1.0f : 0.0f);
        arc_out[(size_t)bi*N + j] = score;
        sv[j] = score; si[j] = j;
        __syncthreads();
        for (int s = 64; s; s >>= 1) {
            if (j < s) {
                float ov = sv[j+s]; int oi = si[j+s];
                if (ov > sv[j] || (ov == sv[j] && oi < si[j])) { sv[j] = ov; si[j] = oi; }
            }
            __syncthreads();
        }
        if (j == 0) tree_out[bi] = (float)si[0];
        __syncthreads();
    }
}

// ---------------------------------------------------------------------------
// K5: rel scores + argmax. One block (64 threads) per bt.
// ---------------------------------------------------------------------------
__global__ void rel_kernel(const float* __restrict__ s3, const float* __restrict__ rh,
                           const float* __restrict__ lsW, const float* __restrict__ lsb,
                           float* __restrict__ rel_out, float* __restrict__ pred_out) {
    int bt = blockIdx.x;
    int t = threadIdx.x;          // 64 threads

    __shared__ float tv[HID];
    __shared__ float sv[64];
    __shared__ int   si[64];

    for (int h = t; h < HID; h += 64)
        tv[h] = fast_tanh(s3[(size_t)bt*300 + 200 + h] + rh[(size_t)bt*HID + h]);
    __syncthreads();

    float score = -1e30f;
    if (t < L) {
        float acc = 0.0f;
        const float* wrow = lsW + t*HID;
        for (int h = 0; h < HID; h++) acc = fmaf(wrow[h], tv[h], acc);
        score = acc + lsb[t];
        rel_out[(size_t)bt*L + t] = score;
    }
    sv[t] = score;
    si[t] = t;
    __syncthreads();
    for (int s = 32; s; s >>= 1) {
        if (t < s) {
            float ov = sv[t + s]; int oi = si[t + s];
            if (ov > sv[t] || (ov == sv[t] && oi < si[t])) { sv[t] = ov; si[t] = oi; }
        }
        __syncthreads();
    }
    if (t == 0) pred_out[bt] = (float)si[0];
}

// ---------------------------------------------------------------------------
extern "C" void kernel_launch(void* const* d_in, const int* in_sizes, int n_in,
                              void* d_out, int out_size, void* d_ws, size_t ws_size,
                              hipStream_t stream) {
    const int*   word_ids    = (const int*)  d_in[0];
    const int*   upos_ids    = (const int*)  d_in[1];
    const int*   target_arcs = (const int*)  d_in[2];
    const float* wlookup     = (const float*)d_in[3];
    const float* tlookup     = (const float*)d_in[4];
    const float* l0f_Wih = (const float*)d_in[5];
    const float* l0f_Whh = (const float*)d_in[6];
    const float* l0f_b   = (const float*)d_in[7];
    const float* l0b_Wih = (const float*)d_in[8];
    const float* l0b_Whh = (const float*)d_in[9];
    const float* l0b_b   = (const float*)d_in[10];
    const float* l1f_Wih = (const float*)d_in[11];
    const float* l1f_Whh = (const float*)d_in[12];
    const float* l1f_b   = (const float*)d_in[13];
    const float* l1b_Wih = (const float*)d_in[14];
    const float* l1b_Whh = (const float*)d_in[15];
    const float* l1b_b   = (const float*)d_in[16];
    const float* eh_W = (const float*)d_in[17];
    const float* eh_b = (const float*)d_in[18];
    const float* em_W = (const float*)d_in[19];
    const float* em_b = (const float*)d_in[20];
    const float* es_W = (const float*)d_in[21];
    const float* es_b = (const float*)d_in[22];
    const float* lh_W = (const float*)d_in[23];
    const float* lh_b = (const float*)d_in[24];
    const float* lm_W = (const float*)d_in[25];
    const float* lm_b = (const float*)d_in[26];
    const float* ls_W = (const float*)d_in[27];
    const float* ls_b = (const float*)d_in[28];

    float* out = (float*)d_out;
    float* trees_out = out;                         // 4096
    float* preds_out = out + BT;                    // 4096
    float* arc_out   = out + 2*BT;                  // 524288
    float* rel_out   = out + 2*BT + BT*N;           // 204800

    float* ws = (float*)d_ws;
    float* A       = ws;                    // 4,096,000: xg fused [m][1000]; later s3 [m][300]
    float* words   = ws + 4096000;          //   512,000
    float* C       = ws + 4608000;          // 1,024,000: h0, then ex
    float* WT_l0   = ws + 5632000;          //   125,000  [125][1000]
    float* WT_l1   = ws + 5757000;          //   250,000  [250][1000]
    float* WT_s3   = ws + 6007000;          //    75,000  [250][300]
    float* WT_lh   = ws + 6082000;          //    25,000  [250][100]
    float* WhT_l0f = ws + 6107000;          //    62,500  [125][500]
    float* WhT_l0b = ws + 6169500;          //    62,500
    float* WhT_l1f = ws + 6232000;          //    62,500
    float* WhT_l1b = ws + 6294500;          //    62,500
    float* b_l0    = ws + 6357000;          //     1,000
    float* b_l1    = ws + 6358000;          //     1,000
    float* b_s3    = ws + 6359000;          //     1,000 (300 used)
    float* rel_head = ws + 6360000;         //   409,600  [m][100]
    // total 6,769,600 floats = 27.1 MB

    // 0. fused biases + one fused tiled transpose for all 12 weight matrices
    bias_setup<<<9, 256, 0, stream>>>(l0f_b, l0b_b, l1f_b, l1b_b, eh_b, em_b, lm_b,
                                      b_l0, b_l1, b_s3);
    {
        TArgs ta{};
        auto tiles = [](int R, int C_) { return ((C_+31)/32) * ((R+31)/32); };
        struct { const float* s; float* d; int R, C, ldo, coff; } js[12] = {
            { l0f_Wih, WT_l0, 500, 125, 1000, 0 },
            { l0b_Wih, WT_l0, 500, 125, 1000, 500 },
            { l1f_Wih, WT_l1, 500, 250, 1000, 0 },
            { l1b_Wih, WT_l1, 500, 250, 1000, 500 },
            { eh_W, WT_s3, 100, 250, 300, 0 },
            { em_W, WT_s3, 100, 250, 300, 100 },
            { lm_W, WT_s3, 100, 250, 300, 200 },
            { lh_W, WT_lh, 100, 250, 100, 0 },
            { l0f_Whh, WhT_l0f, 500, 125, 500, 0 },
            { l0b_Whh, WhT_l0b, 500, 125, 500, 0 },
            { l1f_Whh, WhT_l1f, 500, 125, 500, 0 },
            { l1b_Whh, WhT_l1b, 500, 125, 500, 0 },
        };
        int t0 = 0;
        for (int i = 0; i < 12; i++) {
            ta.j[i].src = js[i].s;  ta.j[i].dst = js[i].d;
            ta.j[i].R = js[i].R;    ta.j[i].C = js[i].C;
            ta.j[i].ldo = js[i].ldo; ta.j[i].coff = js[i].coff;
            ta.j[i].tile0 = t0;
            ta.j[i].tiles_x = (js[i].C + 31) / 32;
            t0 += tiles(js[i].R, js[i].C);
        }
        transpose_fused<<<t0, dim3(32, 8), 0, stream>>>(ta);
    }

    // 1. embeddings
    embed_kernel<<<BT, 128, 0, stream>>>(word_ids, upos_ids, wlookup, tlookup, words);

    // 2. layer-0 input projections, fused fwd+bwd (K=125, N=1000)
    proj_t<2><<<BT/MT, 512, 0, stream>>>(words, WT_l0, b_l0, A, 1000, D, D, nullptr);

    // 3. layer-0 scan -> h0 (C)
    lstm_scan<<<B*2, 512, 0, stream>>>(A, WhT_l0f, WhT_l0b, C);

    // 4. layer-1 input projections (K=250, N=1000)
    proj_t<2><<<BT/MT, 512, 0, stream>>>(C, WT_l1, b_l1, A, 1000, H2, H2, nullptr);

    // 5. layer-1 scan -> ex (C, overwrites h0)
    lstm_scan<<<B*2, 512, 0, stream>>>(A, WhT_l1f, WhT_l1b, C);

    // 6. scorer projections: eh+em+lm fused (N=300) into A; lh gathered (N=100)
    proj_t<2><<<BT/MT, 192, 0, stream>>>(C, WT_s3, b_s3, A, 300, H2, H2, nullptr);
    proj_t<1><<<BT/MT, 128, 0, stream>>>(C, WT_lh, lh_b, rel_head, 100, H2, H2, target_arcs);

    // 7. arc scores + margin + argmax
    arc_kernel<<<BT/ITILE, 128, 0, stream>>>(A, es_W, es_b, target_arcs,
                                             arc_out, trees_out);

    // 8. rel scores + argmax
    rel_kernel<<<BT, 64, 0, stream>>>(A, rel_head, ls_W, ls_b, rel_out, preds_out);
}

// Round 6
// 720.742 us; speedup vs baseline: 1.0767x; 1.0195x over previous
//
#include <hip/hip_runtime.h>
#include <hip/hip_bf16.h>
#include <math.h>

// Problem constants
#define B 32
#define N 128
#define BT (B*N)          // 4096
#define WD 100
#define UD 25
#define D 125             // LSTM hidden per direction
#define G4 (4*D)          // 500 gates
#define H2 (2*D)          // 250
#define HID 100
#define L 50

// Fast, overflow-safe activations on v_exp_f32
__device__ __forceinline__ float fast_tanh(float x) {
    float e = __expf(2.0f * x);
    return 1.0f - 2.0f / (e + 1.0f);
}
__device__ __forceinline__ float fast_sigmoid(float x) {
    return 1.0f / (1.0f + __expf(-x));
}
__device__ __forceinline__ float bcast_lane(float v, int k) {
    return __builtin_bit_cast(float, __builtin_amdgcn_readlane(__builtin_bit_cast(int, v), k));
}

// 125-way macro repetition (named scalars; see rounds 2-5 VGPR=76 saga)
#define REP125(X) \
 X(0) X(1) X(2) X(3) X(4) X(5) X(6) X(7) X(8) X(9) \
 X(10) X(11) X(12) X(13) X(14) X(15) X(16) X(17) X(18) X(19) \
 X(20) X(21) X(22) X(23) X(24) X(25) X(26) X(27) X(28) X(29) \
 X(30) X(31) X(32) X(33) X(34) X(35) X(36) X(37) X(38) X(39) \
 X(40) X(41) X(42) X(43) X(44) X(45) X(46) X(47) X(48) X(49) \
 X(50) X(51) X(52) X(53) X(54) X(55) X(56) X(57) X(58) X(59) \
 X(60) X(61) X(62) X(63) X(64) X(65) X(66) X(67) X(68) X(69) \
 X(70) X(71) X(72) X(73) X(74) X(75) X(76) X(77) X(78) X(79) \
 X(80) X(81) X(82) X(83) X(84) X(85) X(86) X(87) X(88) X(89) \
 X(90) X(91) X(92) X(93) X(94) X(95) X(96) X(97) X(98) X(99) \
 X(100) X(101) X(102) X(103) X(104) X(105) X(106) X(107) X(108) X(109) \
 X(110) X(111) X(112) X(113) X(114) X(115) X(116) X(117) X(118) X(119) \
 X(120) X(121) X(122) X(123) X(124)

// ---------------------------------------------------------------------------
// K0a: combined-bias setup (b_l0[1000], b_l1[1000], b_s3[300])
// ---------------------------------------------------------------------------
__global__ void bias_setup(const float* __restrict__ l0f_b, const float* __restrict__ l0b_b,
                           const float* __restrict__ l1f_b, const float* __restrict__ l1b_b,
                           const float* __restrict__ eh_b, const float* __restrict__ em_b,
                           const float* __restrict__ lm_b,
                           float* __restrict__ b_l0, float* __restrict__ b_l1,
                           float* __restrict__ b_s3) {
    int t = blockIdx.x * blockDim.x + threadIdx.x;
    if (t < 500)        b_l0[t] = l0f_b[t];
    else if (t < 1000)  b_l0[t] = l0b_b[t-500];
    else if (t < 1500)  b_l1[t-1000] = l1f_b[t-1000];
    else if (t < 2000)  b_l1[t-1000] = l1b_b[t-1500];
    else if (t < 2100)  b_s3[t-2000] = eh_b[t-2000];
    else if (t < 2200)  b_s3[t-2000] = em_b[t-2100];
    else if (t < 2300)  b_s3[t-2000] = lm_b[t-2200];
}

// ---------------------------------------------------------------------------
// K0b: fused LDS-tiled transpose. out[k*ldo + coff + n] = in[n*C + k].
// ---------------------------------------------------------------------------
struct TJob { const float* src; float* dst; int R, C, ldo, coff, tile0, tiles_x; };
struct TArgs { TJob j[12]; };

__global__ __launch_bounds__(256)
void transpose_fused(TArgs a) {
    int bid = blockIdx.x;
    int ji = 0;
    #pragma unroll
    for (int i = 1; i < 12; i++) if (bid >= a.j[i].tile0) ji = i;
    TJob jb = a.j[ji];
    int t = bid - jb.tile0;
    int tx = t % jb.tiles_x;        // tile along C (k)
    int ty = t / jb.tiles_x;        // tile along R (n)
    __shared__ float tile[32][33];
    int k0 = tx*32, n0 = ty*32;
    #pragma unroll
    for (int dy = 0; dy < 32; dy += 8) {
        int n = n0 + threadIdx.y + dy;
        int k = k0 + threadIdx.x;
        if (n < jb.R && k < jb.C)
            tile[threadIdx.y+dy][threadIdx.x] = jb.src[(size_t)n*jb.C + k];
    }
    __syncthreads();
    #pragma unroll
    for (int dy = 0; dy < 32; dy += 8) {
        int k = k0 + threadIdx.y + dy;
        int n = n0 + threadIdx.x;
        if (k < jb.C && n < jb.R)
            jb.dst[(size_t)k*jb.ldo + jb.coff + n] = tile[threadIdx.x][threadIdx.y+dy];
    }
}

// ---------------------------------------------------------------------------
// K1: embedding gather
// ---------------------------------------------------------------------------
__global__ void embed_kernel(const int* __restrict__ wids, const int* __restrict__ uids,
                             const float* __restrict__ wl, const float* __restrict__ tl,
                             float* __restrict__ words) {
    int bt = blockIdx.x;
    int t = threadIdx.x;           // 128 threads
    int wid = wids[bt];
    int uid = uids[bt];
    if (t < WD)       words[bt*D + t] = wl[wid*WD + t];
    else if (t < D)   words[bt*D + t] = tl[uid*UD + (t - WD)];
}

// ---------------------------------------------------------------------------
// K2: projection GEMM, transposed weights, CPT columns per thread.
// ---------------------------------------------------------------------------
#define MT 16
template<int CPT>
__global__ __launch_bounds__(512)
void proj_t(const float* __restrict__ x, const float* __restrict__ WT,
            const float* __restrict__ bias, float* __restrict__ out,
            int Ncols, int K, int ldx, const int* __restrict__ gather_idx) {
    __shared__ float xs[250 * 17 + 16];   // xs[k*17 + r]
    int m0 = blockIdx.x * MT;
    // flat cooperative staging: ~MT*K/bd outstanding loads instead of 16 serial
    for (int e = threadIdx.x; e < MT * K; e += blockDim.x) {
        int r = e / K, k = e - r * K;
        int m = m0 + r;
        int row = m;
        if (gather_idx) {
            int bb = m >> 7, np = m & 127;
            row = (bb << 7) + (np == 0 ? 0 : gather_idx[m]);
        }
        xs[k*17 + r] = x[(size_t)row*ldx + k];
    }
    __syncthreads();
    int n0 = threadIdx.x;
    int lane = threadIdx.x & 63;
    int bd = blockDim.x;
    float acc[CPT][MT];
    int ncl[CPT];
    #pragma unroll
    for (int j = 0; j < CPT; j++) {
        int n = n0 + j*bd;
        ncl[j] = (n < Ncols) ? n : (Ncols - 1);
        #pragma unroll
        for (int r = 0; r < MT; r++) acc[j][r] = 0.0f;
    }
    int k0 = 0;
    for (; k0 + 4 <= K; k0 += 4) {
        float xv = xs[(k0 + (lane >> 4))*17 + (lane & 15)];
        float wk[4][CPT];
        #pragma unroll
        for (int q = 0; q < 4; q++)
            #pragma unroll
            for (int j = 0; j < CPT; j++)
                wk[q][j] = WT[(size_t)(k0 + q)*Ncols + ncl[j]];
        #pragma unroll
        for (int q = 0; q < 4; q++) {
            #pragma unroll
            for (int r = 0; r < 16; r++) {
                float hv = bcast_lane(xv, q*16 + r);
                #pragma unroll
                for (int j = 0; j < CPT; j++)
                    acc[j][r] = fmaf(wk[q][j], hv, acc[j][r]);
            }
        }
    }
    for (; k0 < K; k0++) {                 // tail (K=125 -> 1, K=250 -> 2)
        float xv = xs[k0*17 + (lane & 15)];
        float wk[CPT];
        #pragma unroll
        for (int j = 0; j < CPT; j++) wk[j] = WT[(size_t)k0*Ncols + ncl[j]];
        #pragma unroll
        for (int r = 0; r < 16; r++) {
            float hv = bcast_lane(xv, r);
            #pragma unroll
            for (int j = 0; j < CPT; j++)
                acc[j][r] = fmaf(wk[j], hv, acc[j][r]);
        }
    }
    #pragma unroll
    for (int j = 0; j < CPT; j++) {
        int n = n0 + j*bd;
        if (n < Ncols) {
            float bb = bias[n];
            #pragma unroll
            for (int r = 0; r < MT; r++) out[(size_t)(m0 + r)*Ncols + n] = acc[j][r] + bb;
        }
    }
}

// ---------------------------------------------------------------------------
// K3: LSTM scan. One block per (batch, direction); 512 threads.
//     amdgpu_waves_per_eu(2,2): clamp occupancy ceiling so the scheduler/RA
//     stops remat'ing the 125 weight loads into the t-loop (VGPR=76 saga,
//     rounds 2-5). Budget 256 VGPR/wave; ~150 needed. asm pins block remat.
// ---------------------------------------------------------------------------
__global__ __launch_bounds__(512)
__attribute__((amdgpu_waves_per_eu(2, 2)))
void lstm_scan(const float* __restrict__ xgc,
               const float* __restrict__ WhTf, const float* __restrict__ WhTb,
               float* __restrict__ out) {
    int dir = blockIdx.x & 1;
    int b = blockIdx.x >> 1;
    const float* WhT = dir ? WhTb : WhTf;   // [125][500]
    int off = dir ? D : 0;
    int g = threadIdx.x;
    int lane = g & 63;
    bool active = (g < G4);
    int gc = active ? g : (G4 - 1);

    __shared__ float hbuf[128];
    __shared__ float gbuf[G4];

#define DECLW(i) float w##i = WhT[(size_t)(i)*G4 + gc];
    REP125(DECLW)
#undef DECLW
#define PINW(i) asm volatile("" : "+v"(w##i));
    REP125(PINW)
#undef PINW

    float c = 0.0f;
    if (g < 128) hbuf[g] = 0.0f;
    __syncthreads();

    const float* xb = xgc + (size_t)b * N * 1000 + dir * 500;
    float x_next = active ? xb[(size_t)(dir ? (N-1) : 0) * 1000 + g] : 0.0f;

    for (int t = 0; t < N; t++) {
        int tt = dir ? (N-1-t) : t;
        float x_cur = x_next;
        float xn = 0.0f;
        if (active && t + 1 < N)
            xn = xb[(size_t)(dir ? (tt-1) : (tt+1)) * 1000 + g];
        float h0v = hbuf[lane];
        float h1v = hbuf[64 + lane];
        float a4[4];
        a4[0] = x_cur; a4[1] = 0.0f; a4[2] = 0.0f; a4[3] = 0.0f;
#define FMAW(i) a4[(i)&3] = fmaf(w##i, bcast_lane(((i) < 64) ? h0v : h1v, (i)&63), a4[(i)&3]);
        REP125(FMAW)
#undef FMAW
        x_next = xn;
        if (active) gbuf[g] = (a4[0] + a4[1]) + (a4[2] + a4[3]);
        __syncthreads();
        if (g < D) {
            float iv = gbuf[g], fv = gbuf[D+g], gv = gbuf[2*D+g], ov = gbuf[3*D+g];
            float si = fast_sigmoid(iv);
            float sf = fast_sigmoid(fv);
            float so = fast_sigmoid(ov);
            c = sf * c + si * fast_tanh(gv);
            float h = so * fast_tanh(c);
            hbuf[g] = h;
            out[(size_t)(b*N + tt)*H2 + off + g] = h;
        }
        __syncthreads();
    }
}

// ---------------------------------------------------------------------------
// K4: arc scores + margin + argmax. Block per (b, 4-i tile); 128 threads (j).
// ---------------------------------------------------------------------------
#define ITILE 4
__global__ __launch_bounds__(128)
void arc_kernel(const float* __restrict__ s3,
                const float* __restrict__ esW, const float* __restrict__ esb,
                const int* __restrict__ ta,
                float* __restrict__ arc_out, float* __restrict__ tree_out) {
    int blk = blockIdx.x;             // b*32 + it
    int b = blk >> 5, it = blk & 31;
    int j = threadIdx.x;              // 128 threads

    __shared__ float wms[128 * 101];
    __shared__ float whs[ITILE][HID];
    __shared__ float es[HID];
    __shared__ float sv[128];
    __shared__ int   si[128];

    for (int e = j; e < 128 * HID; e += 128) {
        int r = e / HID, h = e - r * HID;
        wms[r*101 + h] = s3[(size_t)(b*N + r)*300 + 100 + h];
    }
    for (int e = j; e < ITILE * HID; e += 128) {
        int ii = e / HID, h = e - ii * HID;
        whs[ii][h] = s3[(size_t)(b*N + it*ITILE + ii)*300 + h];
    }
    if (j < HID) es[j] = esW[j];
    __syncthreads();

    float eb = esb[0];
    const float* wmr = &wms[j * 101];
    for (int ii = 0; ii < ITILE; ii++) {
        int i = it * ITILE + ii;
        int bi = b * N + i;
        float acc = 0.0f;
        for (int h = 0; h < HID; h++)
            acc = fmaf(es[h], fast_tanh(whs[ii][h] + wmr[h]), acc);
        int tai = (i == 0) ? 0 : ta[bi];
        float score = acc + eb + 1.0f - ((j == tai) ? 1.0f : 0.0f);
        arc_out[(size_t)bi*N + j] = score;
        sv[j] = score; si[j] = j;
        __syncthreads();
        for (int s = 64; s; s >>= 1) {
            if (j < s) {
                float ov = sv[j+s]; int oi = si[j+s];
                if (ov > sv[j] || (ov == sv[j] && oi < si[j])) { sv[j] = ov; si[j] = oi; }
            }
            __syncthreads();
        }
        if (j == 0) tree_out[bi] = (float)si[0];
        __syncthreads();
    }
}

// ---------------------------------------------------------------------------
// K5: rel scores + argmax. One block (64 threads) per bt.
// ---------------------------------------------------------------------------
__global__ void rel_kernel(const float* __restrict__ s3, const float* __restrict__ rh,
                           const float* __restrict__ lsW, const float* __restrict__ lsb,
                           float* __restrict__ rel_out, float* __restrict__ pred_out) {
    int bt = blockIdx.x;
    int t = threadIdx.x;          // 64 threads

    __shared__ float tv[HID];
    __shared__ float sv[64];
    __shared__ int   si[64];

    for (int h = t; h < HID; h += 64)
        tv[h] = fast_tanh(s3[(size_t)bt*300 + 200 + h] + rh[(size_t)bt*HID + h]);
    __syncthreads();

    float score = -1e30f;
    if (t < L) {
        float acc = 0.0f;
        const float* wrow = lsW + t*HID;
        for (int h = 0; h < HID; h++) acc = fmaf(wrow[h], tv[h], acc);
        score = acc + lsb[t];
        rel_out[(size_t)bt*L + t] = score;
    }
    sv[t] = score;
    si[t] = t;
    __syncthreads();
    for (int s = 32; s; s >>= 1) {
        if (t < s) {
            float ov = sv[t + s]; int oi = si[t + s];
            if (ov > sv[t] || (ov == sv[t] && oi < si[t])) { sv[t] = ov; si[t] = oi; }
        }
        __syncthreads();
    }
    if (t == 0) pred_out[bt] = (float)si[0];
}

// ---------------------------------------------------------------------------
extern "C" void kernel_launch(void* const* d_in, const int* in_sizes, int n_in,
                              void* d_out, int out_size, void* d_ws, size_t ws_size,
                              hipStream_t stream) {
    const int*   word_ids    = (const int*)  d_in[0];
    const int*   upos_ids    = (const int*)  d_in[1];
    const int*   target_arcs = (const int*)  d_in[2];
    const float* wlookup     = (const float*)d_in[3];
    const float* tlookup     = (const float*)d_in[4];
    const float* l0f_Wih = (const float*)d_in[5];
    const float* l0f_Whh = (const float*)d_in[6];
    const float* l0f_b   = (const float*)d_in[7];
    const float* l0b_Wih = (const float*)d_in[8];
    const float* l0b_Whh = (const float*)d_in[9];
    const float* l0b_b   = (const float*)d_in[10];
    const float* l1f_Wih = (const float*)d_in[11];
    const float* l1f_Whh = (const float*)d_in[12];
    const float* l1f_b   = (const float*)d_in[13];
    const float* l1b_Wih = (const float*)d_in[14];
    const float* l1b_Whh = (const float*)d_in[15];
    const float* l1b_b   = (const float*)d_in[16];
    const float* eh_W = (const float*)d_in[17];
    const float* eh_b = (const float*)d_in[18];
    const float* em_W = (const float*)d_in[19];
    const float* em_b = (const float*)d_in[20];
    const float* es_W = (const float*)d_in[21];
    const float* es_b = (const float*)d_in[22];
    const float* lh_W = (const float*)d_in[23];
    const float* lh_b = (const float*)d_in[24];
    const float* lm_W = (const float*)d_in[25];
    const float* lm_b = (const float*)d_in[26];
    const float* ls_W = (const float*)d_in[27];
    const float* ls_b = (const float*)d_in[28];

    float* out = (float*)d_out;
    float* trees_out = out;                         // 4096
    float* preds_out = out + BT;                    // 4096
    float* arc_out   = out + 2*BT;                  // 524288
    float* rel_out   = out + 2*BT + BT*N;           // 204800

    float* ws = (float*)d_ws;
    float* A       = ws;                    // 4,096,000: xg fused [m][1000]; later s3 [m][300]
    float* words   = ws + 4096000;          //   512,000
    float* C       = ws + 4608000;          // 1,024,000: h0, then ex
    float* WT_l0   = ws + 5632000;          //   125,000  [125][1000]
    float* WT_l1   = ws + 5757000;          //   250,000  [250][1000]
    float* WT_s3   = ws + 6007000;          //    75,000  [250][300]
    float* WT_lh   = ws + 6082000;          //    25,000  [250][100]
    float* WhT_l0f = ws + 6107000;          //    62,500  [125][500]
    float* WhT_l0b = ws + 6169500;          //    62,500
    float* WhT_l1f = ws + 6232000;          //    62,500
    float* WhT_l1b = ws + 6294500;          //    62,500
    float* b_l0    = ws + 6357000;          //     1,000
    float* b_l1    = ws + 6358000;          //     1,000
    float* b_s3    = ws + 6359000;          //     1,000 (300 used)
    float* rel_head = ws + 6360000;         //   409,600  [m][100]
    // total 6,769,600 floats = 27.1 MB

    // 0. fused biases + one fused tiled transpose for all 12 weight matrices
    bias_setup<<<9, 256, 0, stream>>>(l0f_b, l0b_b, l1f_b, l1b_b, eh_b, em_b, lm_b,
                                      b_l0, b_l1, b_s3);
    {
        TArgs ta{};
        auto tiles = [](int R, int C_) { return ((C_+31)/32) * ((R+31)/32); };
        struct { const float* s; float* d; int R, C, ldo, coff; } js[12] = {
            { l0f_Wih, WT_l0, 500, 125, 1000, 0 },
            { l0b_Wih, WT_l0, 500, 125, 1000, 500 },
            { l1f_Wih, WT_l1, 500, 250, 1000, 0 },
            { l1b_Wih, WT_l1, 500, 250, 1000, 500 },
            { eh_W, WT_s3, 100, 250, 300, 0 },
            { em_W, WT_s3, 100, 250, 300, 100 },
            { lm_W, WT_s3, 100, 250, 300, 200 },
            { lh_W, WT_lh, 100, 250, 100, 0 },
            { l0f_Whh, WhT_l0f, 500, 125, 500, 0 },
            { l0b_Whh, WhT_l0b, 500, 125, 500, 0 },
            { l1f_Whh, WhT_l1f, 500, 125, 500, 0 },
            { l1b_Whh, WhT_l1b, 500, 125, 500, 0 },
        };
        int t0 = 0;
        for (int i = 0; i < 12; i++) {
            ta.j[i].src = js[i].s;  ta.j[i].dst = js[i].d;
            ta.j[i].R = js[i].R;    ta.j[i].C = js[i].C;
            ta.j[i].ldo = js[i].ldo; ta.j[i].coff = js[i].coff;
            ta.j[i].tile0 = t0;
            ta.j[i].tiles_x = (js[i].C + 31) / 32;
            t0 += tiles(js[i].R, js[i].C);
        }
        transpose_fused<<<t0, dim3(32, 8), 0, stream>>>(ta);
    }

    // 1. embeddings
    embed_kernel<<<BT, 128, 0, stream>>>(word_ids, upos_ids, wlookup, tlookup, words);

    // 2. layer-0 input projections, fused fwd+bwd (K=125, N=1000)
    proj_t<2><<<BT/MT, 512, 0, stream>>>(words, WT_l0, b_l0, A, 1000, D, D, nullptr);

    // 3. layer-0 scan -> h0 (C)
    lstm_scan<<<B*2, 512, 0, stream>>>(A, WhT_l0f, WhT_l0b, C);

    // 4. layer-1 input projections (K=250, N=1000)
    proj_t<2><<<BT/MT, 512, 0, stream>>>(C, WT_l1, b_l1, A, 1000, H2, H2, nullptr);

    // 5. layer-1 scan -> ex (C, overwrites h0)
    lstm_scan<<<B*2, 512, 0, stream>>>(A, WhT_l1f, WhT_l1b, C);

    // 6. scorer projections: eh+em+lm fused (N=300) into A; lh gathered (N=100)
    proj_t<2><<<BT/MT, 192, 0, stream>>>(C, WT_s3, b_s3, A, 300, H2, H2, nullptr);
    proj_t<1><<<BT/MT, 128, 0, stream>>>(C, WT_lh, lh_b, rel_head, 100, H2, H2, target_arcs);

    // 7. arc scores + margin + argmax
    arc_kernel<<<BT/ITILE, 128, 0, stream>>>(A, es_W, es_b, target_arcs,
                                             arc_out, trees_out);

    // 8. rel scores + argmax
    rel_kernel<<<BT, 64, 0, stream>>>(A, rel_head, ls_W, ls_b, rel_out, preds_out);
}

// Round 7
// 646.855 us; speedup vs baseline: 1.1996x; 1.1142x over previous
//
#include <hip/hip_runtime.h>
#include <hip/hip_bf16.h>
#include <math.h>

// Problem constants
#define B 32
#define N 128
#define BT (B*N)          // 4096
#define WD 100
#define UD 25
#define D 125             // LSTM hidden per direction
#define G4 (4*D)          // 500 gates
#define H2 (2*D)          // 250
#define HID 100
#define L 50

// Fast, overflow-safe activations on v_exp_f32
__device__ __forceinline__ float fast_tanh(float x) {
    float e = __expf(2.0f * x);
    return 1.0f - 2.0f / (e + 1.0f);
}
__device__ __forceinline__ float fast_sigmoid(float x) {
    return 1.0f / (1.0f + __expf(-x));
}
__device__ __forceinline__ float bcast_lane(float v, int k) {
    return __builtin_bit_cast(float, __builtin_amdgcn_readlane(__builtin_bit_cast(int, v), k));
}

// 64-way macro repetition: per-thread weight cache small enough (~64+20 live)
// to sit under the allocator's revealed ~88-VGPR ceiling (rounds 2-6 saga).
#define REP64(X) \
 X(0) X(1) X(2) X(3) X(4) X(5) X(6) X(7) X(8) X(9) \
 X(10) X(11) X(12) X(13) X(14) X(15) X(16) X(17) X(18) X(19) \
 X(20) X(21) X(22) X(23) X(24) X(25) X(26) X(27) X(28) X(29) \
 X(30) X(31) X(32) X(33) X(34) X(35) X(36) X(37) X(38) X(39) \
 X(40) X(41) X(42) X(43) X(44) X(45) X(46) X(47) X(48) X(49) \
 X(50) X(51) X(52) X(53) X(54) X(55) X(56) X(57) X(58) X(59) \
 X(60) X(61) X(62) X(63)

// ---------------------------------------------------------------------------
// K0a: combined-bias setup (b_l0[1000], b_l1[1000], b_s3[300])
// ---------------------------------------------------------------------------
__global__ void bias_setup(const float* __restrict__ l0f_b, const float* __restrict__ l0b_b,
                           const float* __restrict__ l1f_b, const float* __restrict__ l1b_b,
                           const float* __restrict__ eh_b, const float* __restrict__ em_b,
                           const float* __restrict__ lm_b,
                           float* __restrict__ b_l0, float* __restrict__ b_l1,
                           float* __restrict__ b_s3) {
    int t = blockIdx.x * blockDim.x + threadIdx.x;
    if (t < 500)        b_l0[t] = l0f_b[t];
    else if (t < 1000)  b_l0[t] = l0b_b[t-500];
    else if (t < 1500)  b_l1[t-1000] = l1f_b[t-1000];
    else if (t < 2000)  b_l1[t-1000] = l1b_b[t-1500];
    else if (t < 2100)  b_s3[t-2000] = eh_b[t-2000];
    else if (t < 2200)  b_s3[t-2000] = em_b[t-2100];
    else if (t < 2300)  b_s3[t-2000] = lm_b[t-2200];
}

// K0c: zero the pad rows (125..128) of the 4 WhT buffers
__global__ void pad_zero(float* __restrict__ w0, float* __restrict__ w1,
                         float* __restrict__ w2, float* __restrict__ w3) {
    int t = blockIdx.x * blockDim.x + threadIdx.x;   // 4 * 1516 = 6064 elems
    int m = t / 1516, e = t % 1516;
    float* p = (m == 0) ? w0 : (m == 1) ? w1 : (m == 2) ? w2 : w3;
    p[125*500 + e] = 0.0f;                           // covers 125*500 .. 128*500+16
}

// ---------------------------------------------------------------------------
// K0b: fused LDS-tiled transpose. out[k*ldo + coff + n] = in[n*C + k].
// ---------------------------------------------------------------------------
struct TJob { const float* src; float* dst; int R, C, ldo, coff, tile0, tiles_x; };
struct TArgs { TJob j[12]; };

__global__ __launch_bounds__(256)
void transpose_fused(TArgs a) {
    int bid = blockIdx.x;
    int ji = 0;
    #pragma unroll
    for (int i = 1; i < 12; i++) if (bid >= a.j[i].tile0) ji = i;
    TJob jb = a.j[ji];
    int t = bid - jb.tile0;
    int tx = t % jb.tiles_x;        // tile along C (k)
    int ty = t / jb.tiles_x;        // tile along R (n)
    __shared__ float tile[32][33];
    int k0 = tx*32, n0 = ty*32;
    #pragma unroll
    for (int dy = 0; dy < 32; dy += 8) {
        int n = n0 + threadIdx.y + dy;
        int k = k0 + threadIdx.x;
        if (n < jb.R && k < jb.C)
            tile[threadIdx.y+dy][threadIdx.x] = jb.src[(size_t)n*jb.C + k];
    }
    __syncthreads();
    #pragma unroll
    for (int dy = 0; dy < 32; dy += 8) {
        int k = k0 + threadIdx.y + dy;
        int n = n0 + threadIdx.x;
        if (k < jb.C && n < jb.R)
            jb.dst[(size_t)k*jb.ldo + jb.coff + n] = tile[threadIdx.x][threadIdx.y+dy];
    }
}

// ---------------------------------------------------------------------------
// K1: embedding gather
// ---------------------------------------------------------------------------
__global__ void embed_kernel(const int* __restrict__ wids, const int* __restrict__ uids,
                             const float* __restrict__ wl, const float* __restrict__ tl,
                             float* __restrict__ words) {
    int bt = blockIdx.x;
    int t = threadIdx.x;           // 128 threads
    int wid = wids[bt];
    int uid = uids[bt];
    if (t < WD)       words[bt*D + t] = wl[wid*WD + t];
    else if (t < D)   words[bt*D + t] = tl[uid*UD + (t - WD)];
}

// ---------------------------------------------------------------------------
// K2: projection GEMM, transposed weights, CPT columns per thread,
//     software-pipelined WT loads (prefetch next k-group).
// ---------------------------------------------------------------------------
#define MT 16
template<int CPT>
__global__ __launch_bounds__(512)
void proj_t(const float* __restrict__ x, const float* __restrict__ WT,
            const float* __restrict__ bias, float* __restrict__ out,
            int Ncols, int K, int ldx, const int* __restrict__ gather_idx) {
    __shared__ float xs[250 * 17 + 16];   // xs[k*17 + r]
    int m0 = blockIdx.x * MT;
    for (int e = threadIdx.x; e < MT * K; e += blockDim.x) {
        int r = e / K, k = e - r * K;
        int m = m0 + r;
        int row = m;
        if (gather_idx) {
            int bb = m >> 7, np = m & 127;
            row = (bb << 7) + (np == 0 ? 0 : gather_idx[m]);
        }
        xs[k*17 + r] = x[(size_t)row*ldx + k];
    }
    __syncthreads();
    int n0 = threadIdx.x;
    int lane = threadIdx.x & 63;
    int bd = blockDim.x;
    float acc[CPT][MT];
    int ncl[CPT];
    #pragma unroll
    for (int j = 0; j < CPT; j++) {
        int n = n0 + j*bd;
        ncl[j] = (n < Ncols) ? n : (Ncols - 1);
        #pragma unroll
        for (int r = 0; r < MT; r++) acc[j][r] = 0.0f;
    }
    float wkc[4][CPT];
    #pragma unroll
    for (int q = 0; q < 4; q++)
        #pragma unroll
        for (int j = 0; j < CPT; j++)
            wkc[q][j] = WT[(size_t)q*Ncols + ncl[j]];     // K >= 4 always
    int k0 = 0;
    for (; k0 + 8 <= K; k0 += 4) {
        float xv = xs[(k0 + (lane >> 4))*17 + (lane & 15)];
        float wkn[4][CPT];
        #pragma unroll
        for (int q = 0; q < 4; q++)
            #pragma unroll
            for (int j = 0; j < CPT; j++)
                wkn[q][j] = WT[(size_t)(k0 + 4 + q)*Ncols + ncl[j]];
        #pragma unroll
        for (int q = 0; q < 4; q++) {
            #pragma unroll
            for (int r = 0; r < 16; r++) {
                float hv = bcast_lane(xv, q*16 + r);
                #pragma unroll
                for (int j = 0; j < CPT; j++)
                    acc[j][r] = fmaf(wkc[q][j], hv, acc[j][r]);
            }
        }
        #pragma unroll
        for (int q = 0; q < 4; q++)
            #pragma unroll
            for (int j = 0; j < CPT; j++)
                wkc[q][j] = wkn[q][j];
    }
    { // last full group
        float xv = xs[(k0 + (lane >> 4))*17 + (lane & 15)];
        #pragma unroll
        for (int q = 0; q < 4; q++) {
            #pragma unroll
            for (int r = 0; r < 16; r++) {
                float hv = bcast_lane(xv, q*16 + r);
                #pragma unroll
                for (int j = 0; j < CPT; j++)
                    acc[j][r] = fmaf(wkc[q][j], hv, acc[j][r]);
            }
        }
        k0 += 4;
    }
    for (; k0 < K; k0++) {                 // tail (K=125 -> 1, K=250 -> 2)
        float xv = xs[k0*17 + (lane & 15)];
        float wk[CPT];
        #pragma unroll
        for (int j = 0; j < CPT; j++) wk[j] = WT[(size_t)k0*Ncols + ncl[j]];
        #pragma unroll
        for (int r = 0; r < 16; r++) {
            float hv = bcast_lane(xv, r);
            #pragma unroll
            for (int j = 0; j < CPT; j++)
                acc[j][r] = fmaf(wk[j], hv, acc[j][r]);
        }
    }
    #pragma unroll
    for (int j = 0; j < CPT; j++) {
        int n = n0 + j*bd;
        if (n < Ncols) {
            float bb = bias[n];
            #pragma unroll
            for (int r = 0; r < MT; r++) out[(size_t)(m0 + r)*Ncols + n] = acc[j][r] + bb;
        }
    }
}

// ---------------------------------------------------------------------------
// K3: LSTM scan, k-split. 1024 threads per (b,dir): thread = (gate g, k-half).
//     Each thread holds 64 weights (fits under the ~88-VGPR allocator ceiling
//     observed rounds 2-6). Partials combined via pbuf in LDS.
//     WhT is [128][500] with rows 125..127 zeroed (pad contributes 0).
// ---------------------------------------------------------------------------
__global__
__attribute__((amdgpu_flat_work_group_size(1024, 1024), amdgpu_waves_per_eu(4, 4)))
void lstm_scan(const float* __restrict__ xgc,
               const float* __restrict__ WhTf, const float* __restrict__ WhTb,
               float* __restrict__ out) {
    int dir = blockIdx.x & 1;
    int b = blockIdx.x >> 1;
    const float* WhT = dir ? WhTb : WhTf;   // [128][500], zero-padded
    int off = dir ? D : 0;
    int t = threadIdx.x;
    int g = t & 511;
    int half = t >> 9;
    int lane = t & 63;
    int kbase = half << 6;                  // 0 or 64

    __shared__ float hbuf[128];
    __shared__ float pbuf[1024];

    const float* wbase = WhT + (size_t)kbase * 500 + g;
#define DECLW(i) float w##i = wbase[(size_t)(i)*500];
    REP64(DECLW)
#undef DECLW
#define PINW(i) asm volatile("" : "+v"(w##i));
    REP64(PINW)
#undef PINW

    float c = 0.0f;
    if (t < 128) hbuf[t] = 0.0f;
    __syncthreads();

    const float* xb = xgc + (size_t)b * N * 1000 + dir * 500;
    bool xa = (half == 0) && (g < G4);
    float x_next = xa ? xb[(size_t)(dir ? (N-1) : 0) * 1000 + g] : 0.0f;

    for (int ti = 0; ti < N; ti++) {
        int tt = dir ? (N-1-ti) : ti;
        float x_cur = x_next;
        float xn = 0.0f;
        if (xa && ti + 1 < N)
            xn = xb[(size_t)(dir ? (tt-1) : (tt+1)) * 1000 + g];
        float hseg = hbuf[kbase + lane];     // lane i holds h[kbase+i]
        float a4[4];
        a4[0] = x_cur; a4[1] = 0.0f; a4[2] = 0.0f; a4[3] = 0.0f;
#define FMAW(i) a4[(i)&3] = fmaf(w##i, bcast_lane(hseg, i), a4[(i)&3]);
        REP64(FMAW)
#undef FMAW
        x_next = xn;
        pbuf[t] = (a4[0] + a4[1]) + (a4[2] + a4[3]);
        __syncthreads();
        if (t < D) {
            float iv = pbuf[t]       + pbuf[512 + t];
            float fv = pbuf[D+t]     + pbuf[512 + D+t];
            float gv = pbuf[2*D+t]   + pbuf[512 + 2*D+t];
            float ov = pbuf[3*D+t]   + pbuf[512 + 3*D+t];
            float si = fast_sigmoid(iv);
            float sf = fast_sigmoid(fv);
            float so = fast_sigmoid(ov);
            c = sf * c + si * fast_tanh(gv);
            float h = so * fast_tanh(c);
            hbuf[t] = h;
            out[(size_t)(b*N + tt)*H2 + off + t] = h;
        }
        __syncthreads();
    }
}

// ---------------------------------------------------------------------------
// K4: arc scores + margin + argmax. Block per (b, 4-i tile); 128 threads (j).
// ---------------------------------------------------------------------------
#define ITILE 4
__global__ __launch_bounds__(128)
void arc_kernel(const float* __restrict__ s3,
                const float* __restrict__ esW, const float* __restrict__ esb,
                const int* __restrict__ ta,
                float* __restrict__ arc_out, float* __restrict__ tree_out) {
    int blk = blockIdx.x;             // b*32 + it
    int b = blk >> 5, it = blk & 31;
    int j = threadIdx.x;              // 128 threads

    __shared__ float wms[128 * 101];
    __shared__ float whs[ITILE][HID];
    __shared__ float es[HID];
    __shared__ float sv[128];
    __shared__ int   si[128];

    for (int e = j; e < 128 * HID; e += 128) {
        int r = e / HID, h = e - r * HID;
        wms[r*101 + h] = s3[(size_t)(b*N + r)*300 + 100 + h];
    }
    for (int e = j; e < ITILE * HID; e += 128) {
        int ii = e / HID, h = e - ii * HID;
        whs[ii][h] = s3[(size_t)(b*N + it*ITILE + ii)*300 + h];
    }
    if (j < HID) es[j] = esW[j];
    __syncthreads();

    float eb = esb[0];
    const float* wmr = &wms[j * 101];
    for (int ii = 0; ii < ITILE; ii++) {
        int i = it * ITILE + ii;
        int bi = b * N + i;
        float acc = 0.0f;
        for (int h = 0; h < HID; h++)
            acc = fmaf(es[h], fast_tanh(whs[ii][h] + wmr[h]), acc);
        int tai = (i == 0) ? 0 : ta[bi];
        float score = acc + eb + 1.0f - ((j == tai) ? 1.0f : 0.0f);
        arc_out[(size_t)bi*N + j] = score;
        sv[j] = score; si[j] = j;
        __syncthreads();
        for (int s = 64; s; s >>= 1) {
            if (j < s) {
                float ov = sv[j+s]; int oi = si[j+s];
                if (ov > sv[j] || (ov == sv[j] && oi < si[j])) { sv[j] = ov; si[j] = oi; }
            }
            __syncthreads();
        }
        if (j == 0) tree_out[bi] = (float)si[0];
        __syncthreads();
    }
}

// ---------------------------------------------------------------------------
// K5: rel scores + argmax. One block (64 threads) per bt.
// ---------------------------------------------------------------------------
__global__ void rel_kernel(const float* __restrict__ s3, const float* __restrict__ rh,
                           const float* __restrict__ lsW, const float* __restrict__ lsb,
                           float* __restrict__ rel_out, float* __restrict__ pred_out) {
    int bt = blockIdx.x;
    int t = threadIdx.x;          // 64 threads

    __shared__ float tv[HID];
    __shared__ float sv[64];
    __shared__ int   si[64];

    for (int h = t; h < HID; h += 64)
        tv[h] = fast_tanh(s3[(size_t)bt*300 + 200 + h] + rh[(size_t)bt*HID + h]);
    __syncthreads();

    float score = -1e30f;
    if (t < L) {
        float acc = 0.0f;
        const float* wrow = lsW + t*HID;
        for (int h = 0; h < HID; h++) acc = fmaf(wrow[h], tv[h], acc);
        score = acc + lsb[t];
        rel_out[(size_t)bt*L + t] = score;
    }
    sv[t] = score;
    si[t] = t;
    __syncthreads();
    for (int s = 32; s; s >>= 1) {
        if (t < s) {
            float ov = sv[t + s]; int oi = si[t + s];
            if (ov > sv[t] || (ov == sv[t] && oi < si[t])) { sv[t] = ov; si[t] = oi; }
        }
        __syncthreads();
    }
    if (t == 0) pred_out[bt] = (float)si[0];
}

// ---------------------------------------------------------------------------
extern "C" void kernel_launch(void* const* d_in, const int* in_sizes, int n_in,
                              void* d_out, int out_size, void* d_ws, size_t ws_size,
                              hipStream_t stream) {
    const int*   word_ids    = (const int*)  d_in[0];
    const int*   upos_ids    = (const int*)  d_in[1];
    const int*   target_arcs = (const int*)  d_in[2];
    const float* wlookup     = (const float*)d_in[3];
    const float* tlookup     = (const float*)d_in[4];
    const float* l0f_Wih = (const float*)d_in[5];
    const float* l0f_Whh = (const float*)d_in[6];
    const float* l0f_b   = (const float*)d_in[7];
    const float* l0b_Wih = (const float*)d_in[8];
    const float* l0b_Whh = (const float*)d_in[9];
    const float* l0b_b   = (const float*)d_in[10];
    const float* l1f_Wih = (const float*)d_in[11];
    const float* l1f_Whh = (const float*)d_in[12];
    const float* l1f_b   = (const float*)d_in[13];
    const float* l1b_Wih = (const float*)d_in[14];
    const float* l1b_Whh = (const float*)d_in[15];
    const float* l1b_b   = (const float*)d_in[16];
    const float* eh_W = (const float*)d_in[17];
    const float* eh_b = (const float*)d_in[18];
    const float* em_W = (const float*)d_in[19];
    const float* em_b = (const float*)d_in[20];
    const float* es_W = (const float*)d_in[21];
    const float* es_b = (const float*)d_in[22];
    const float* lh_W = (const float*)d_in[23];
    const float* lh_b = (const float*)d_in[24];
    const float* lm_W = (const float*)d_in[25];
    const float* lm_b = (const float*)d_in[26];
    const float* ls_W = (const float*)d_in[27];
    const float* ls_b = (const float*)d_in[28];

    float* out = (float*)d_out;
    float* trees_out = out;                         // 4096
    float* preds_out = out + BT;                    // 4096
    float* arc_out   = out + 2*BT;                  // 524288
    float* rel_out   = out + 2*BT + BT*N;           // 204800

    float* ws = (float*)d_ws;
    float* A       = ws;                    // 4,096,000: xg fused [m][1000]; later s3 [m][300]
    float* words   = ws + 4096000;          //   512,000
    float* C       = ws + 4608000;          // 1,024,000: h0, then ex
    float* WT_l0   = ws + 5632000;          //   125,000  [125][1000]
    float* WT_l1   = ws + 5757000;          //   250,000  [250][1000]
    float* WT_s3   = ws + 6007000;          //    75,000  [250][300]
    float* WT_lh   = ws + 6082000;          //    25,000  [250][100]
    float* WhT_l0f = ws + 6107000;          //    64,016  [128][500]+16 (pad rows zeroed)
    float* WhT_l0b = ws + 6171016;          //    64,016
    float* WhT_l1f = ws + 6235032;          //    64,016
    float* WhT_l1b = ws + 6299048;          //    64,016
    float* b_l0    = ws + 6363064;          //     1,000
    float* b_l1    = ws + 6364064;          //     1,000
    float* b_s3    = ws + 6365064;          //     1,000 (300 used)
    float* rel_head = ws + 6366064;         //   409,600  [m][100]
    // total 6,775,664 floats = 27.1 MB

    // 0. fused biases + pad-row zeroing + fused tiled transpose (12 matrices)
    bias_setup<<<9, 256, 0, stream>>>(l0f_b, l0b_b, l1f_b, l1b_b, eh_b, em_b, lm_b,
                                      b_l0, b_l1, b_s3);
    pad_zero<<<24, 256, 0, stream>>>(WhT_l0f, WhT_l0b, WhT_l1f, WhT_l1b);
    {
        TArgs ta{};
        auto tiles = [](int R, int C_) { return ((C_+31)/32) * ((R+31)/32); };
        struct { const float* s; float* d; int R, C, ldo, coff; } js[12] = {
            { l0f_Wih, WT_l0, 500, 125, 1000, 0 },
            { l0b_Wih, WT_l0, 500, 125, 1000, 500 },
            { l1f_Wih, WT_l1, 500, 250, 1000, 0 },
            { l1b_Wih, WT_l1, 500, 250, 1000, 500 },
            { eh_W, WT_s3, 100, 250, 300, 0 },
            { em_W, WT_s3, 100, 250, 300, 100 },
            { lm_W, WT_s3, 100, 250, 300, 200 },
            { lh_W, WT_lh, 100, 250, 100, 0 },
            { l0f_Whh, WhT_l0f, 500, 125, 500, 0 },
            { l0b_Whh, WhT_l0b, 500, 125, 500, 0 },
            { l1f_Whh, WhT_l1f, 500, 125, 500, 0 },
            { l1b_Whh, WhT_l1b, 500, 125, 500, 0 },
        };
        int t0 = 0;
        for (int i = 0; i < 12; i++) {
            ta.j[i].src = js[i].s;  ta.j[i].dst = js[i].d;
            ta.j[i].R = js[i].R;    ta.j[i].C = js[i].C;
            ta.j[i].ldo = js[i].ldo; ta.j[i].coff = js[i].coff;
            ta.j[i].tile0 = t0;
            ta.j[i].tiles_x = (js[i].C + 31) / 32;
            t0 += tiles(js[i].R, js[i].C);
        }
        transpose_fused<<<t0, dim3(32, 8), 0, stream>>>(ta);
    }

    // 1. embeddings
    embed_kernel<<<BT, 128, 0, stream>>>(word_ids, upos_ids, wlookup, tlookup, words);

    // 2. layer-0 input projections, fused fwd+bwd (K=125, N=1000)
    proj_t<2><<<BT/MT, 512, 0, stream>>>(words, WT_l0, b_l0, A, 1000, D, D, nullptr);

    // 3. layer-0 scan -> h0 (C)
    lstm_scan<<<B*2, 1024, 0, stream>>>(A, WhT_l0f, WhT_l0b, C);

    // 4. layer-1 input projections (K=250, N=1000)
    proj_t<2><<<BT/MT, 512, 0, stream>>>(C, WT_l1, b_l1, A, 1000, H2, H2, nullptr);

    // 5. layer-1 scan -> ex (C, overwrites h0)
    lstm_scan<<<B*2, 1024, 0, stream>>>(A, WhT_l1f, WhT_l1b, C);

    // 6. scorer projections: eh+em+lm fused (N=300) into A; lh gathered (N=100)
    proj_t<2><<<BT/MT, 192, 0, stream>>>(C, WT_s3, b_s3, A, 300, H2, H2, nullptr);
    proj_t<1><<<BT/MT, 128, 0, stream>>>(C, WT_lh, lh_b, rel_head, 100, H2, H2, target_arcs);

    // 7. arc scores + margin + argmax
    arc_kernel<<<BT/ITILE, 128, 0, stream>>>(A, es_W, es_b, target_arcs,
                                             arc_out, trees_out);

    // 8. rel scores + argmax
    rel_kernel<<<BT, 64, 0, stream>>>(A, rel_head, ls_W, ls_b, rel_out, preds_out);
}

// Round 8
// 640.110 us; speedup vs baseline: 1.2123x; 1.0105x over previous
//
#include <hip/hip_runtime.h>
#include <hip/hip_bf16.h>
#include <math.h>

// Problem constants
#define B 32
#define N 128
#define BT (B*N)          // 4096
#define WD 100
#define UD 25
#define D 125             // LSTM hidden per direction
#define G4 (4*D)          // 500 gates
#define H2 (2*D)          // 250
#define HID 100
#define L 50

// Fast, overflow-safe activations on v_exp_f32
__device__ __forceinline__ float fast_tanh(float x) {
    float e = __expf(2.0f * x);
    return 1.0f - 2.0f / (e + 1.0f);
}
__device__ __forceinline__ float fast_sigmoid(float x) {
    return 1.0f / (1.0f + __expf(-x));
}
__device__ __forceinline__ float bcast_lane(float v, int k) {
    return __builtin_bit_cast(float, __builtin_amdgcn_readlane(__builtin_bit_cast(int, v), k));
}

// 64-way macro repetition
#define REP64(X) \
 X(0) X(1) X(2) X(3) X(4) X(5) X(6) X(7) X(8) X(9) \
 X(10) X(11) X(12) X(13) X(14) X(15) X(16) X(17) X(18) X(19) \
 X(20) X(21) X(22) X(23) X(24) X(25) X(26) X(27) X(28) X(29) \
 X(30) X(31) X(32) X(33) X(34) X(35) X(36) X(37) X(38) X(39) \
 X(40) X(41) X(42) X(43) X(44) X(45) X(46) X(47) X(48) X(49) \
 X(50) X(51) X(52) X(53) X(54) X(55) X(56) X(57) X(58) X(59) \
 X(60) X(61) X(62) X(63)

// ---------------------------------------------------------------------------
// K0a: combined-bias setup (b_l0[1000], b_l1[1000], b_s3[300])
// ---------------------------------------------------------------------------
__global__ void bias_setup(const float* __restrict__ l0f_b, const float* __restrict__ l0b_b,
                           const float* __restrict__ l1f_b, const float* __restrict__ l1b_b,
                           const float* __restrict__ eh_b, const float* __restrict__ em_b,
                           const float* __restrict__ lm_b,
                           float* __restrict__ b_l0, float* __restrict__ b_l1,
                           float* __restrict__ b_s3) {
    int t = blockIdx.x * blockDim.x + threadIdx.x;
    if (t < 500)        b_l0[t] = l0f_b[t];
    else if (t < 1000)  b_l0[t] = l0b_b[t-500];
    else if (t < 1500)  b_l1[t-1000] = l1f_b[t-1000];
    else if (t < 2000)  b_l1[t-1000] = l1b_b[t-1500];
    else if (t < 2100)  b_s3[t-2000] = eh_b[t-2000];
    else if (t < 2200)  b_s3[t-2000] = em_b[t-2100];
    else if (t < 2300)  b_s3[t-2000] = lm_b[t-2200];
}

// K0c: zero the pad rows (125..128) of the 4 WhT buffers
__global__ void pad_zero(float* __restrict__ w0, float* __restrict__ w1,
                         float* __restrict__ w2, float* __restrict__ w3) {
    int t = blockIdx.x * blockDim.x + threadIdx.x;   // 4 * 1516 = 6064 elems
    int m = t / 1516, e = t % 1516;
    float* p = (m == 0) ? w0 : (m == 1) ? w1 : (m == 2) ? w2 : w3;
    p[125*500 + e] = 0.0f;                           // covers 125*500 .. 128*500+16
}

// ---------------------------------------------------------------------------
// K0b: fused LDS-tiled transpose. out[k*ldo + coff + n] = in[n*C + k].
// ---------------------------------------------------------------------------
struct TJob { const float* src; float* dst; int R, C, ldo, coff, tile0, tiles_x; };
struct TArgs { TJob j[12]; };

__global__ __launch_bounds__(256)
void transpose_fused(TArgs a) {
    int bid = blockIdx.x;
    int ji = 0;
    #pragma unroll
    for (int i = 1; i < 12; i++) if (bid >= a.j[i].tile0) ji = i;
    TJob jb = a.j[ji];
    int t = bid - jb.tile0;
    int tx = t % jb.tiles_x;        // tile along C (k)
    int ty = t / jb.tiles_x;        // tile along R (n)
    __shared__ float tile[32][33];
    int k0 = tx*32, n0 = ty*32;
    #pragma unroll
    for (int dy = 0; dy < 32; dy += 8) {
        int n = n0 + threadIdx.y + dy;
        int k = k0 + threadIdx.x;
        if (n < jb.R && k < jb.C)
            tile[threadIdx.y+dy][threadIdx.x] = jb.src[(size_t)n*jb.C + k];
    }
    __syncthreads();
    #pragma unroll
    for (int dy = 0; dy < 32; dy += 8) {
        int k = k0 + threadIdx.y + dy;
        int n = n0 + threadIdx.x;
        if (k < jb.C && n < jb.R)
            jb.dst[(size_t)k*jb.ldo + jb.coff + n] = tile[threadIdx.x][threadIdx.y+dy];
    }
}

// ---------------------------------------------------------------------------
// K1: embedding gather
// ---------------------------------------------------------------------------
__global__ void embed_kernel(const int* __restrict__ wids, const int* __restrict__ uids,
                             const float* __restrict__ wl, const float* __restrict__ tl,
                             float* __restrict__ words) {
    int bt = blockIdx.x;
    int t = threadIdx.x;           // 128 threads
    int wid = wids[bt];
    int uid = uids[bt];
    if (t < WD)       words[bt*D + t] = wl[wid*WD + t];
    else if (t < D)   words[bt*D + t] = tl[uid*UD + (t - WD)];
}

// ---------------------------------------------------------------------------
// K2: projection GEMM, transposed weights, CPT columns per thread,
//     software-pipelined WT loads (prefetch next k-group).
// ---------------------------------------------------------------------------
#define MT 16
template<int CPT>
__global__ __launch_bounds__(512)
void proj_t(const float* __restrict__ x, const float* __restrict__ WT,
            const float* __restrict__ bias, float* __restrict__ out,
            int Ncols, int K, int ldx, const int* __restrict__ gather_idx) {
    __shared__ float xs[250 * 17 + 16];   // xs[k*17 + r]
    int m0 = blockIdx.x * MT;
    for (int e = threadIdx.x; e < MT * K; e += blockDim.x) {
        int r = e / K, k = e - r * K;
        int m = m0 + r;
        int row = m;
        if (gather_idx) {
            int bb = m >> 7, np = m & 127;
            row = (bb << 7) + (np == 0 ? 0 : gather_idx[m]);
        }
        xs[k*17 + r] = x[(size_t)row*ldx + k];
    }
    __syncthreads();
    int n0 = threadIdx.x;
    int lane = threadIdx.x & 63;
    int bd = blockDim.x;
    float acc[CPT][MT];
    int ncl[CPT];
    #pragma unroll
    for (int j = 0; j < CPT; j++) {
        int n = n0 + j*bd;
        ncl[j] = (n < Ncols) ? n : (Ncols - 1);
        #pragma unroll
        for (int r = 0; r < MT; r++) acc[j][r] = 0.0f;
    }
    float wkc[4][CPT];
    #pragma unroll
    for (int q = 0; q < 4; q++)
        #pragma unroll
        for (int j = 0; j < CPT; j++)
            wkc[q][j] = WT[(size_t)q*Ncols + ncl[j]];     // K >= 4 always
    int k0 = 0;
    for (; k0 + 8 <= K; k0 += 4) {
        float xv = xs[(k0 + (lane >> 4))*17 + (lane & 15)];
        float wkn[4][CPT];
        #pragma unroll
        for (int q = 0; q < 4; q++)
            #pragma unroll
            for (int j = 0; j < CPT; j++)
                wkn[q][j] = WT[(size_t)(k0 + 4 + q)*Ncols + ncl[j]];
        #pragma unroll
        for (int q = 0; q < 4; q++) {
            #pragma unroll
            for (int r = 0; r < 16; r++) {
                float hv = bcast_lane(xv, q*16 + r);
                #pragma unroll
                for (int j = 0; j < CPT; j++)
                    acc[j][r] = fmaf(wkc[q][j], hv, acc[j][r]);
            }
        }
        #pragma unroll
        for (int q = 0; q < 4; q++)
            #pragma unroll
            for (int j = 0; j < CPT; j++)
                wkc[q][j] = wkn[q][j];
    }
    { // last full group
        float xv = xs[(k0 + (lane >> 4))*17 + (lane & 15)];
        #pragma unroll
        for (int q = 0; q < 4; q++) {
            #pragma unroll
            for (int r = 0; r < 16; r++) {
                float hv = bcast_lane(xv, q*16 + r);
                #pragma unroll
                for (int j = 0; j < CPT; j++)
                    acc[j][r] = fmaf(wkc[q][j], hv, acc[j][r]);
            }
        }
        k0 += 4;
    }
    for (; k0 < K; k0++) {                 // tail (K=125 -> 1, K=250 -> 2)
        float xv = xs[k0*17 + (lane & 15)];
        float wk[CPT];
        #pragma unroll
        for (int j = 0; j < CPT; j++) wk[j] = WT[(size_t)k0*Ncols + ncl[j]];
        #pragma unroll
        for (int r = 0; r < 16; r++) {
            float hv = bcast_lane(xv, r);
            #pragma unroll
            for (int j = 0; j < CPT; j++)
                acc[j][r] = fmaf(wk[j], hv, acc[j][r]);
        }
    }
    #pragma unroll
    for (int j = 0; j < CPT; j++) {
        int n = n0 + j*bd;
        if (n < Ncols) {
            float bb = bias[n];
            #pragma unroll
            for (int r = 0; r < MT; r++) out[(size_t)(m0 + r)*Ncols + n] = acc[j][r] + bb;
        }
    }
}

// ---------------------------------------------------------------------------
// K3: LSTM scan, k-split. 1024 threads per (b,dir): thread = (gate g, k-half).
//     Weights loaded via inline-asm global_load_dword (saddr form): asm-defined
//     values are NOT rematerializable, so RA must keep them in VGPRs
//     (64 w + ~30 live < 128 budget at 4 waves/EU). Rounds 2-7: every
//     source-level pinning trick failed (VGPR 76/76/76/88/52 = remat'd loads).
// ---------------------------------------------------------------------------
__global__
__attribute__((amdgpu_flat_work_group_size(1024, 1024), amdgpu_waves_per_eu(4, 4)))
void lstm_scan(const float* __restrict__ xgc,
               const float* __restrict__ WhTf, const float* __restrict__ WhTb,
               float* __restrict__ out) {
    int dir = blockIdx.x & 1;
    int b = blockIdx.x >> 1;
    const float* WhT = dir ? WhTb : WhTf;   // [128][500], zero-padded rows 125..127
    int off = dir ? D : 0;
    int t = threadIdx.x;
    int g = t & 511;
    int half = t >> 9;
    int lane = t & 63;
    int kbase = half << 6;                  // 0 or 64

    __shared__ float hbuf[128];
    __shared__ float pbuf[1024];

    // voffset (bytes) for row kbase+i, col g; max (127*500+511)*4 = 256,044 < 2^32
    unsigned voff0 = ((unsigned)kbase * 500u + (unsigned)g) * 4u;
#define DECLW(i) float w##i; \
    asm volatile("global_load_dword %0, %1, %2" \
                 : "=v"(w##i) : "v"(voff0 + (unsigned)(i)*2000u), "s"(WhT));
    REP64(DECLW)
#undef DECLW
    asm volatile("s_waitcnt vmcnt(0)" ::: "memory");

    float c = 0.0f;
    if (t < 128) hbuf[t] = 0.0f;
    __syncthreads();

    const float* xb = xgc + (size_t)b * N * 1000 + dir * 500;
    bool xa = (half == 0) && (g < G4);
    float x_next = xa ? xb[(size_t)(dir ? (N-1) : 0) * 1000 + g] : 0.0f;

    for (int ti = 0; ti < N; ti++) {
        int tt = dir ? (N-1-ti) : ti;
        float x_cur = x_next;
        float xn = 0.0f;
        if (xa && ti + 1 < N)
            xn = xb[(size_t)(dir ? (tt-1) : (tt+1)) * 1000 + g];
        float hseg = hbuf[kbase + lane];     // lane i holds h[kbase+i]
        float a4[4];
        a4[0] = x_cur; a4[1] = 0.0f; a4[2] = 0.0f; a4[3] = 0.0f;
#define FMAW(i) a4[(i)&3] = fmaf(w##i, bcast_lane(hseg, i), a4[(i)&3]);
        REP64(FMAW)
#undef FMAW
        x_next = xn;
        pbuf[t] = (a4[0] + a4[1]) + (a4[2] + a4[3]);
        __syncthreads();
        if (t < D) {
            float iv = pbuf[t]       + pbuf[512 + t];
            float fv = pbuf[D+t]     + pbuf[512 + D+t];
            float gv = pbuf[2*D+t]   + pbuf[512 + 2*D+t];
            float ov = pbuf[3*D+t]   + pbuf[512 + 3*D+t];
            float si = fast_sigmoid(iv);
            float sf = fast_sigmoid(fv);
            float so = fast_sigmoid(ov);
            c = sf * c + si * fast_tanh(gv);
            float h = so * fast_tanh(c);
            hbuf[t] = h;
            out[(size_t)(b*N + tt)*H2 + off + t] = h;
        }
        __syncthreads();
    }
}

// ---------------------------------------------------------------------------
// K4: arc scores + margin + argmax. Block per (b, 4-i tile); 128 threads (j).
// ---------------------------------------------------------------------------
#define ITILE 4
__global__ __launch_bounds__(128)
void arc_kernel(const float* __restrict__ s3,
                const float* __restrict__ esW, const float* __restrict__ esb,
                const int* __restrict__ ta,
                float* __restrict__ arc_out, float* __restrict__ tree_out) {
    int blk = blockIdx.x;             // b*32 + it
    int b = blk >> 5, it = blk & 31;
    int j = threadIdx.x;              // 128 threads

    __shared__ float wms[128 * 101];
    __shared__ float whs[ITILE][HID];
    __shared__ float es[HID];
    __shared__ float sv[128];
    __shared__ int   si[128];

    for (int e = j; e < 128 * HID; e += 128) {
        int r = e / HID, h = e - r * HID;
        wms[r*101 + h] = s3[(size_t)(b*N + r)*300 + 100 + h];
    }
    for (int e = j; e < ITILE * HID; e += 128) {
        int ii = e / HID, h = e - ii * HID;
        whs[ii][h] = s3[(size_t)(b*N + it*ITILE + ii)*300 + h];
    }
    if (j < HID) es[j] = esW[j];
    __syncthreads();

    float eb = esb[0];
    const float* wmr = &wms[j * 101];
    for (int ii = 0; ii < ITILE; ii++) {
        int i = it * ITILE + ii;
        int bi = b * N + i;
        float acc = 0.0f;
        for (int h = 0; h < HID; h++)
            acc = fmaf(es[h], fast_tanh(whs[ii][h] + wmr[h]), acc);
        int tai = (i == 0) ? 0 : ta[bi];
        float score = acc + eb + 1.0f - ((j == tai) ? 1.0f : 0.0f);
        arc_out[(size_t)bi*N + j] = score;
        sv[j] = score; si[j] = j;
        __syncthreads();
        for (int s = 64; s; s >>= 1) {
            if (j < s) {
                float ov = sv[j+s]; int oi = si[j+s];
                if (ov > sv[j] || (ov == sv[j] && oi < si[j])) { sv[j] = ov; si[j] = oi; }
            }
            __syncthreads();
        }
        if (j == 0) tree_out[bi] = (float)si[0];
        __syncthreads();
    }
}

// ---------------------------------------------------------------------------
// K5: rel scores + argmax. One block (64 threads) per bt.
// ---------------------------------------------------------------------------
__global__ void rel_kernel(const float* __restrict__ s3, const float* __restrict__ rh,
                           const float* __restrict__ lsW, const float* __restrict__ lsb,
                           float* __restrict__ rel_out, float* __restrict__ pred_out) {
    int bt = blockIdx.x;
    int t = threadIdx.x;          // 64 threads

    __shared__ float tv[HID];
    __shared__ float sv[64];
    __shared__ int   si[64];

    for (int h = t; h < HID; h += 64)
        tv[h] = fast_tanh(s3[(size_t)bt*300 + 200 + h] + rh[(size_t)bt*HID + h]);
    __syncthreads();

    float score = -1e30f;
    if (t < L) {
        float acc = 0.0f;
        const float* wrow = lsW + t*HID;
        for (int h = 0; h < HID; h++) acc = fmaf(wrow[h], tv[h], acc);
        score = acc + lsb[t];
        rel_out[(size_t)bt*L + t] = score;
    }
    sv[t] = score;
    si[t] = t;
    __syncthreads();
    for (int s = 32; s; s >>= 1) {
        if (t < s) {
            float ov = sv[t + s]; int oi = si[t + s];
            if (ov > sv[t] || (ov == sv[t] && oi < si[t])) { sv[t] = ov; si[t] = oi; }
        }
        __syncthreads();
    }
    if (t == 0) pred_out[bt] = (float)si[0];
}

// ---------------------------------------------------------------------------
extern "C" void kernel_launch(void* const* d_in, const int* in_sizes, int n_in,
                              void* d_out, int out_size, void* d_ws, size_t ws_size,
                              hipStream_t stream) {
    const int*   word_ids    = (const int*)  d_in[0];
    const int*   upos_ids    = (const int*)  d_in[1];
    const int*   target_arcs = (const int*)  d_in[2];
    const float* wlookup     = (const float*)d_in[3];
    const float* tlookup     = (const float*)d_in[4];
    const float* l0f_Wih = (const float*)d_in[5];
    const float* l0f_Whh = (const float*)d_in[6];
    const float* l0f_b   = (const float*)d_in[7];
    const float* l0b_Wih = (const float*)d_in[8];
    const float* l0b_Whh = (const float*)d_in[9];
    const float* l0b_b   = (const float*)d_in[10];
    const float* l1f_Wih = (const float*)d_in[11];
    const float* l1f_Whh = (const float*)d_in[12];
    const float* l1f_b   = (const float*)d_in[13];
    const float* l1b_Wih = (const float*)d_in[14];
    const float* l1b_Whh = (const float*)d_in[15];
    const float* l1b_b   = (const float*)d_in[16];
    const float* eh_W = (const float*)d_in[17];
    const float* eh_b = (const float*)d_in[18];
    const float* em_W = (const float*)d_in[19];
    const float* em_b = (const float*)d_in[20];
    const float* es_W = (const float*)d_in[21];
    const float* es_b = (const float*)d_in[22];
    const float* lh_W = (const float*)d_in[23];
    const float* lh_b = (const float*)d_in[24];
    const float* lm_W = (const float*)d_in[25];
    const float* lm_b = (const float*)d_in[26];
    const float* ls_W = (const float*)d_in[27];
    const float* ls_b = (const float*)d_in[28];

    float* out = (float*)d_out;
    float* trees_out = out;                         // 4096
    float* preds_out = out + BT;                    // 4096
    float* arc_out   = out + 2*BT;                  // 524288
    float* rel_out   = out + 2*BT + BT*N;           // 204800

    float* ws = (float*)d_ws;
    float* A       = ws;                    // 4,096,000: xg fused [m][1000]; later s3 [m][300]
    float* words   = ws + 4096000;          //   512,000
    float* C       = ws + 4608000;          // 1,024,000: h0, then ex
    float* WT_l0   = ws + 5632000;          //   125,000  [125][1000]
    float* WT_l1   = ws + 5757000;          //   250,000  [250][1000]
    float* WT_s3   = ws + 6007000;          //    75,000  [250][300]
    float* WT_lh   = ws + 6082000;          //    25,000  [250][100]
    float* WhT_l0f = ws + 6107000;          //    64,016  [128][500]+16 (pad rows zeroed)
    float* WhT_l0b = ws + 6171016;          //    64,016
    float* WhT_l1f = ws + 6235032;          //    64,016
    float* WhT_l1b = ws + 6299048;          //    64,016
    float* b_l0    = ws + 6363064;          //     1,000
    float* b_l1    = ws + 6364064;          //     1,000
    float* b_s3    = ws + 6365064;          //     1,000 (300 used)
    float* rel_head = ws + 6366064;         //   409,600  [m][100]
    // total 6,775,664 floats = 27.1 MB

    // 0. fused biases + pad-row zeroing + fused tiled transpose (12 matrices)
    bias_setup<<<9, 256, 0, stream>>>(l0f_b, l0b_b, l1f_b, l1b_b, eh_b, em_b, lm_b,
                                      b_l0, b_l1, b_s3);
    pad_zero<<<24, 256, 0, stream>>>(WhT_l0f, WhT_l0b, WhT_l1f, WhT_l1b);
    {
        TArgs ta{};
        auto tiles = [](int R, int C_) { return ((C_+31)/32) * ((R+31)/32); };
        struct { const float* s; float* d; int R, C, ldo, coff; } js[12] = {
            { l0f_Wih, WT_l0, 500, 125, 1000, 0 },
            { l0b_Wih, WT_l0, 500, 125, 1000, 500 },
            { l1f_Wih, WT_l1, 500, 250, 1000, 0 },
            { l1b_Wih, WT_l1, 500, 250, 1000, 500 },
            { eh_W, WT_s3, 100, 250, 300, 0 },
            { em_W, WT_s3, 100, 250, 300, 100 },
            { lm_W, WT_s3, 100, 250, 300, 200 },
            { lh_W, WT_lh, 100, 250, 100, 0 },
            { l0f_Whh, WhT_l0f, 500, 125, 500, 0 },
            { l0b_Whh, WhT_l0b, 500, 125, 500, 0 },
            { l1f_Whh, WhT_l1f, 500, 125, 500, 0 },
            { l1b_Whh, WhT_l1b, 500, 125, 500, 0 },
        };
        int t0 = 0;
        for (int i = 0; i < 12; i++) {
            ta.j[i].src = js[i].s;  ta.j[i].dst = js[i].d;
            ta.j[i].R = js[i].R;    ta.j[i].C = js[i].C;
            ta.j[i].ldo = js[i].ldo; ta.j[i].coff = js[i].coff;
            ta.j[i].tile0 = t0;
            ta.j[i].tiles_x = (js[i].C + 31) / 32;
            t0 += tiles(js[i].R, js[i].C);
        }
        transpose_fused<<<t0, dim3(32, 8), 0, stream>>>(ta);
    }

    // 1. embeddings
    embed_kernel<<<BT, 128, 0, stream>>>(word_ids, upos_ids, wlookup, tlookup, words);

    // 2. layer-0 input projections, fused fwd+bwd (K=125, N=1000)
    proj_t<2><<<BT/MT, 512, 0, stream>>>(words, WT_l0, b_l0, A, 1000, D, D, nullptr);

    // 3. layer-0 scan -> h0 (C)
    lstm_scan<<<B*2, 1024, 0, stream>>>(A, WhT_l0f, WhT_l0b, C);

    // 4. layer-1 input projections (K=250, N=1000)
    proj_t<2><<<BT/MT, 512, 0, stream>>>(C, WT_l1, b_l1, A, 1000, H2, H2, nullptr);

    // 5. layer-1 scan -> ex (C, overwrites h0)
    lstm_scan<<<B*2, 1024, 0, stream>>>(A, WhT_l1f, WhT_l1b, C);

    // 6. scorer projections: eh+em+lm fused (N=300) into A; lh gathered (N=100)
    proj_t<2><<<BT/MT, 192, 0, stream>>>(C, WT_s3, b_s3, A, 300, H2, H2, nullptr);
    proj_t<1><<<BT/MT, 128, 0, stream>>>(C, WT_lh, lh_b, rel_head, 100, H2, H2, target_arcs);

    // 7. arc scores + margin + argmax
    arc_kernel<<<BT/ITILE, 128, 0, stream>>>(A, es_W, es_b, target_arcs,
                                             arc_out, trees_out);

    // 8. rel scores + argmax
    rel_kernel<<<BT, 64, 0, stream>>>(A, rel_head, ls_W, ls_b, rel_out, preds_out);
}

// Round 9
// 627.825 us; speedup vs baseline: 1.2360x; 1.0196x over previous
//
#include <hip/hip_runtime.h>
#include <hip/hip_bf16.h>
#include <math.h>

// Problem constants
#define B 32
#define N 128
#define BT (B*N)          // 4096
#define WD 100
#define UD 25
#define D 125             // LSTM hidden per direction
#define G4 (4*D)          // 500 gates
#define H2 (2*D)          // 250
#define HID 100
#define L 50

// Fast, overflow-safe activations on v_exp_f32
__device__ __forceinline__ float fast_tanh(float x) {
    float e = __expf(2.0f * x);
    return 1.0f - 2.0f / (e + 1.0f);
}
__device__ __forceinline__ float fast_sigmoid(float x) {
    return 1.0f / (1.0f + __expf(-x));
}
__device__ __forceinline__ float bcast_lane(float v, int k) {
    return __builtin_bit_cast(float, __builtin_amdgcn_readlane(__builtin_bit_cast(int, v), k));
}

// 64-way macro repetition
#define REP64(X) \
 X(0) X(1) X(2) X(3) X(4) X(5) X(6) X(7) X(8) X(9) \
 X(10) X(11) X(12) X(13) X(14) X(15) X(16) X(17) X(18) X(19) \
 X(20) X(21) X(22) X(23) X(24) X(25) X(26) X(27) X(28) X(29) \
 X(30) X(31) X(32) X(33) X(34) X(35) X(36) X(37) X(38) X(39) \
 X(40) X(41) X(42) X(43) X(44) X(45) X(46) X(47) X(48) X(49) \
 X(50) X(51) X(52) X(53) X(54) X(55) X(56) X(57) X(58) X(59) \
 X(60) X(61) X(62) X(63)

// ---------------------------------------------------------------------------
// K0a: combined-bias setup (b_l0[1000], b_l1[1000], b_s3[300])
// ---------------------------------------------------------------------------
__global__ void bias_setup(const float* __restrict__ l0f_b, const float* __restrict__ l0b_b,
                           const float* __restrict__ l1f_b, const float* __restrict__ l1b_b,
                           const float* __restrict__ eh_b, const float* __restrict__ em_b,
                           const float* __restrict__ lm_b,
                           float* __restrict__ b_l0, float* __restrict__ b_l1,
                           float* __restrict__ b_s3) {
    int t = blockIdx.x * blockDim.x + threadIdx.x;
    if (t < 500)        b_l0[t] = l0f_b[t];
    else if (t < 1000)  b_l0[t] = l0b_b[t-500];
    else if (t < 1500)  b_l1[t-1000] = l1f_b[t-1000];
    else if (t < 2000)  b_l1[t-1000] = l1b_b[t-1500];
    else if (t < 2100)  b_s3[t-2000] = eh_b[t-2000];
    else if (t < 2200)  b_s3[t-2000] = em_b[t-2100];
    else if (t < 2300)  b_s3[t-2000] = lm_b[t-2200];
}

// K0c: zero the pad rows (125..128) of the 4 WhT buffers
__global__ void pad_zero(float* __restrict__ w0, float* __restrict__ w1,
                         float* __restrict__ w2, float* __restrict__ w3) {
    int t = blockIdx.x * blockDim.x + threadIdx.x;   // 4 * 1516 = 6064 elems
    int m = t / 1516, e = t % 1516;
    float* p = (m == 0) ? w0 : (m == 1) ? w1 : (m == 2) ? w2 : w3;
    p[125*500 + e] = 0.0f;                           // covers 125*500 .. 128*500+16
}

// ---------------------------------------------------------------------------
// K0b: fused LDS-tiled transpose. out[k*ldo + coff + n] = in[n*C + k].
// ---------------------------------------------------------------------------
struct TJob { const float* src; float* dst; int R, C, ldo, coff, tile0, tiles_x; };
struct TArgs { TJob j[12]; };

__global__ __launch_bounds__(256)
void transpose_fused(TArgs a) {
    int bid = blockIdx.x;
    int ji = 0;
    #pragma unroll
    for (int i = 1; i < 12; i++) if (bid >= a.j[i].tile0) ji = i;
    TJob jb = a.j[ji];
    int t = bid - jb.tile0;
    int tx = t % jb.tiles_x;        // tile along C (k)
    int ty = t / jb.tiles_x;        // tile along R (n)
    __shared__ float tile[32][33];
    int k0 = tx*32, n0 = ty*32;
    #pragma unroll
    for (int dy = 0; dy < 32; dy += 8) {
        int n = n0 + threadIdx.y + dy;
        int k = k0 + threadIdx.x;
        if (n < jb.R && k < jb.C)
            tile[threadIdx.y+dy][threadIdx.x] = jb.src[(size_t)n*jb.C + k];
    }
    __syncthreads();
    #pragma unroll
    for (int dy = 0; dy < 32; dy += 8) {
        int k = k0 + threadIdx.y + dy;
        int n = n0 + threadIdx.x;
        if (k < jb.C && n < jb.R)
            jb.dst[(size_t)k*jb.ldo + jb.coff + n] = tile[threadIdx.x][threadIdx.y+dy];
    }
}

// ---------------------------------------------------------------------------
// K1: embedding gather
// ---------------------------------------------------------------------------
__global__ void embed_kernel(const int* __restrict__ wids, const int* __restrict__ uids,
                             const float* __restrict__ wl, const float* __restrict__ tl,
                             float* __restrict__ words) {
    int bt = blockIdx.x;
    int t = threadIdx.x;           // 128 threads
    int wid = wids[bt];
    int uid = uids[bt];
    if (t < WD)       words[bt*D + t] = wl[wid*WD + t];
    else if (t < D)   words[bt*D + t] = tl[uid*UD + (t - WD)];
}

// ---------------------------------------------------------------------------
// K2: projection GEMM, transposed weights, CPT columns per thread,
//     software-pipelined WT loads (prefetch next k-group).
// ---------------------------------------------------------------------------
#define MT 16
template<int CPT>
__global__ __launch_bounds__(512)
void proj_t(const float* __restrict__ x, const float* __restrict__ WT,
            const float* __restrict__ bias, float* __restrict__ out,
            int Ncols, int K, int ldx, const int* __restrict__ gather_idx) {
    __shared__ float xs[250 * 17 + 16];   // xs[k*17 + r]
    int m0 = blockIdx.x * MT;
    for (int e = threadIdx.x; e < MT * K; e += blockDim.x) {
        int r = e / K, k = e - r * K;
        int m = m0 + r;
        int row = m;
        if (gather_idx) {
            int bb = m >> 7, np = m & 127;
            row = (bb << 7) + (np == 0 ? 0 : gather_idx[m]);
        }
        xs[k*17 + r] = x[(size_t)row*ldx + k];
    }
    __syncthreads();
    int n0 = threadIdx.x;
    int lane = threadIdx.x & 63;
    int bd = blockDim.x;
    float acc[CPT][MT];
    int ncl[CPT];
    #pragma unroll
    for (int j = 0; j < CPT; j++) {
        int n = n0 + j*bd;
        ncl[j] = (n < Ncols) ? n : (Ncols - 1);
        #pragma unroll
        for (int r = 0; r < MT; r++) acc[j][r] = 0.0f;
    }
    float wkc[4][CPT];
    #pragma unroll
    for (int q = 0; q < 4; q++)
        #pragma unroll
        for (int j = 0; j < CPT; j++)
            wkc[q][j] = WT[(size_t)q*Ncols + ncl[j]];     // K >= 4 always
    int k0 = 0;
    for (; k0 + 8 <= K; k0 += 4) {
        float xv = xs[(k0 + (lane >> 4))*17 + (lane & 15)];
        float wkn[4][CPT];
        #pragma unroll
        for (int q = 0; q < 4; q++)
            #pragma unroll
            for (int j = 0; j < CPT; j++)
                wkn[q][j] = WT[(size_t)(k0 + 4 + q)*Ncols + ncl[j]];
        #pragma unroll
        for (int q = 0; q < 4; q++) {
            #pragma unroll
            for (int r = 0; r < 16; r++) {
                float hv = bcast_lane(xv, q*16 + r);
                #pragma unroll
                for (int j = 0; j < CPT; j++)
                    acc[j][r] = fmaf(wkc[q][j], hv, acc[j][r]);
            }
        }
        #pragma unroll
        for (int q = 0; q < 4; q++)
            #pragma unroll
            for (int j = 0; j < CPT; j++)
                wkc[q][j] = wkn[q][j];
    }
    { // last full group
        float xv = xs[(k0 + (lane >> 4))*17 + (lane & 15)];
        #pragma unroll
        for (int q = 0; q < 4; q++) {
            #pragma unroll
            for (int r = 0; r < 16; r++) {
                float hv = bcast_lane(xv, q*16 + r);
                #pragma unroll
                for (int j = 0; j < CPT; j++)
                    acc[j][r] = fmaf(wkc[q][j], hv, acc[j][r]);
            }
        }
        k0 += 4;
    }
    for (; k0 < K; k0++) {                 // tail (K=125 -> 1, K=250 -> 2)
        float xv = xs[k0*17 + (lane & 15)];
        float wk[CPT];
        #pragma unroll
        for (int j = 0; j < CPT; j++) wk[j] = WT[(size_t)k0*Ncols + ncl[j]];
        #pragma unroll
        for (int r = 0; r < 16; r++) {
            float hv = bcast_lane(xv, r);
            #pragma unroll
            for (int j = 0; j < CPT; j++)
                acc[j][r] = fmaf(wk[j], hv, acc[j][r]);
        }
    }
    #pragma unroll
    for (int j = 0; j < CPT; j++) {
        int n = n0 + j*bd;
        if (n < Ncols) {
            float bb = bias[n];
            #pragma unroll
            for (int r = 0; r < MT; r++) out[(size_t)(m0 + r)*Ncols + n] = acc[j][r] + bb;
        }
    }
}

// ---------------------------------------------------------------------------
// K3: LSTM scan, k-split. 1024 threads per (b,dir): thread = (gate g, k-half).
//     Weights via inline-asm global_load (non-remat). h is broadcast to all
//     lanes via same-address ds_read_b128 (conflict-free broadcast), replacing
//     64 v_readlane with 16 LDS reads: per-step VALU drops ~128 -> ~80 instrs.
//     __launch_bounds__(1024, 4): canonical spelling for 4 waves/EU => 128-reg
//     budget (raw amdgpu_waves_per_eu attr was not honored; rounds 7-8).
// ---------------------------------------------------------------------------
__global__ __launch_bounds__(1024, 4)
void lstm_scan(const float* __restrict__ xgc,
               const float* __restrict__ WhTf, const float* __restrict__ WhTb,
               float* __restrict__ out) {
    int dir = blockIdx.x & 1;
    int b = blockIdx.x >> 1;
    const float* WhT = dir ? WhTb : WhTf;   // [128][500], zero-padded rows 125..127
    int off = dir ? D : 0;
    int t = threadIdx.x;
    int g = t & 511;
    int half = t >> 9;
    int kbase = half << 6;                  // 0 or 64

    __shared__ __align__(16) float hbuf[128];
    __shared__ float pbuf[1024];

    // voffset (bytes) for row kbase+i, col g
    unsigned voff0 = ((unsigned)kbase * 500u + (unsigned)g) * 4u;
#define DECLW(i) float w##i; \
    asm volatile("global_load_dword %0, %1, %2" \
                 : "=v"(w##i) : "v"(voff0 + (unsigned)(i)*2000u), "s"(WhT));
    REP64(DECLW)
#undef DECLW
    asm volatile("s_waitcnt vmcnt(0)" ::: "memory");

    float c = 0.0f;
    if (t < 128) hbuf[t] = 0.0f;
    __syncthreads();

    const float* xb = xgc + (size_t)b * N * 1000 + dir * 500;
    bool xa = (half == 0) && (g < G4);
    float x_next = xa ? xb[(size_t)(dir ? (N-1) : 0) * 1000 + g] : 0.0f;

    const float4* h4q = ((const float4*)hbuf) + (kbase >> 2);

#define FMA4(q, i0, i1, i2, i3) { float4 hv = h4q[q]; \
    a4[0] = fmaf(w##i0, hv.x, a4[0]); \
    a4[1] = fmaf(w##i1, hv.y, a4[1]); \
    a4[2] = fmaf(w##i2, hv.z, a4[2]); \
    a4[3] = fmaf(w##i3, hv.w, a4[3]); }

    for (int ti = 0; ti < N; ti++) {
        int tt = dir ? (N-1-ti) : ti;
        float x_cur = x_next;
        float xn = 0.0f;
        if (xa && ti + 1 < N)
            xn = xb[(size_t)(dir ? (tt-1) : (tt+1)) * 1000 + g];
        float a4[4];
        a4[0] = x_cur; a4[1] = 0.0f; a4[2] = 0.0f; a4[3] = 0.0f;
        FMA4(0,  0,  1,  2,  3)  FMA4(1,  4,  5,  6,  7)
        FMA4(2,  8,  9, 10, 11)  FMA4(3, 12, 13, 14, 15)
        FMA4(4, 16, 17, 18, 19)  FMA4(5, 20, 21, 22, 23)
        FMA4(6, 24, 25, 26, 27)  FMA4(7, 28, 29, 30, 31)
        FMA4(8, 32, 33, 34, 35)  FMA4(9, 36, 37, 38, 39)
        FMA4(10, 40, 41, 42, 43) FMA4(11, 44, 45, 46, 47)
        FMA4(12, 48, 49, 50, 51) FMA4(13, 52, 53, 54, 55)
        FMA4(14, 56, 57, 58, 59) FMA4(15, 60, 61, 62, 63)
        x_next = xn;
        pbuf[t] = (a4[0] + a4[1]) + (a4[2] + a4[3]);
        __syncthreads();
        if (t < D) {
            float iv = pbuf[t]       + pbuf[512 + t];
            float fv = pbuf[D+t]     + pbuf[512 + D+t];
            float gv = pbuf[2*D+t]   + pbuf[512 + 2*D+t];
            float ov = pbuf[3*D+t]   + pbuf[512 + 3*D+t];
            float si = fast_sigmoid(iv);
            float sf = fast_sigmoid(fv);
            float so = fast_sigmoid(ov);
            c = sf * c + si * fast_tanh(gv);
            float h = so * fast_tanh(c);
            hbuf[t] = h;
            out[(size_t)(b*N + tt)*H2 + off + t] = h;
        }
        __syncthreads();
    }
#undef FMA4
}

// ---------------------------------------------------------------------------
// K4: arc scores + margin + argmax. Block per (b, 4-i tile); 128 threads (j).
// ---------------------------------------------------------------------------
#define ITILE 4
__global__ __launch_bounds__(128)
void arc_kernel(const float* __restrict__ s3,
                const float* __restrict__ esW, const float* __restrict__ esb,
                const int* __restrict__ ta,
                float* __restrict__ arc_out, float* __restrict__ tree_out) {
    int blk = blockIdx.x;             // b*32 + it
    int b = blk >> 5, it = blk & 31;
    int j = threadIdx.x;              // 128 threads

    __shared__ float wms[128 * 101];
    __shared__ float whs[ITILE][HID];
    __shared__ float es[HID];
    __shared__ float sv[128];
    __shared__ int   si[128];

    for (int e = j; e < 128 * HID; e += 128) {
        int r = e / HID, h = e - r * HID;
        wms[r*101 + h] = s3[(size_t)(b*N + r)*300 + 100 + h];
    }
    for (int e = j; e < ITILE * HID; e += 128) {
        int ii = e / HID, h = e - ii * HID;
        whs[ii][h] = s3[(size_t)(b*N + it*ITILE + ii)*300 + h];
    }
    if (j < HID) es[j] = esW[j];
    __syncthreads();

    float eb = esb[0];
    const float* wmr = &wms[j * 101];
    for (int ii = 0; ii < ITILE; ii++) {
        int i = it * ITILE + ii;
        int bi = b * N + i;
        float acc = 0.0f;
        for (int h = 0; h < HID; h++)
            acc = fmaf(es[h], fast_tanh(whs[ii][h] + wmr[h]), acc);
        int tai = (i == 0) ? 0 : ta[bi];
        float score = acc + eb + 1.0f - ((j == tai) ? 1.0f : 0.0f);
        arc_out[(size_t)bi*N + j] = score;
        sv[j] = score; si[j] = j;
        __syncthreads();
        for (int s = 64; s; s >>= 1) {
            if (j < s) {
                float ov = sv[j+s]; int oi = si[j+s];
                if (ov > sv[j] || (ov == sv[j] && oi < si[j])) { sv[j] = ov; si[j] = oi; }
            }
            __syncthreads();
        }
        if (j == 0) tree_out[bi] = (float)si[0];
        __syncthreads();
    }
}

// ---------------------------------------------------------------------------
// K5: rel scores + argmax. One block (64 threads) per bt.
// ---------------------------------------------------------------------------
__global__ void rel_kernel(const float* __restrict__ s3, const float* __restrict__ rh,
                           const float* __restrict__ lsW, const float* __restrict__ lsb,
                           float* __restrict__ rel_out, float* __restrict__ pred_out) {
    int bt = blockIdx.x;
    int t = threadIdx.x;          // 64 threads

    __shared__ float tv[HID];
    __shared__ float sv[64];
    __shared__ int   si[64];

    for (int h = t; h < HID; h += 64)
        tv[h] = fast_tanh(s3[(size_t)bt*300 + 200 + h] + rh[(size_t)bt*HID + h]);
    __syncthreads();

    float score = -1e30f;
    if (t < L) {
        float acc = 0.0f;
        const float* wrow = lsW + t*HID;
        for (int h = 0; h < HID; h++) acc = fmaf(wrow[h], tv[h], acc);
        score = acc + lsb[t];
        rel_out[(size_t)bt*L + t] = score;
    }
    sv[t] = score;
    si[t] = t;
    __syncthreads();
    for (int s = 32; s; s >>= 1) {
        if (t < s) {
            float ov = sv[t + s]; int oi = si[t + s];
            if (ov > sv[t] || (ov == sv[t] && oi < si[t])) { sv[t] = ov; si[t] = oi; }
        }
        __syncthreads();
    }
    if (t == 0) pred_out[bt] = (float)si[0];
}

// ---------------------------------------------------------------------------
extern "C" void kernel_launch(void* const* d_in, const int* in_sizes, int n_in,
                              void* d_out, int out_size, void* d_ws, size_t ws_size,
                              hipStream_t stream) {
    const int*   word_ids    = (const int*)  d_in[0];
    const int*   upos_ids    = (const int*)  d_in[1];
    const int*   target_arcs = (const int*)  d_in[2];
    const float* wlookup     = (const float*)d_in[3];
    const float* tlookup     = (const float*)d_in[4];
    const float* l0f_Wih = (const float*)d_in[5];
    const float* l0f_Whh = (const float*)d_in[6];
    const float* l0f_b   = (const float*)d_in[7];
    const float* l0b_Wih = (const float*)d_in[8];
    const float* l0b_Whh = (const float*)d_in[9];
    const float* l0b_b   = (const float*)d_in[10];
    const float* l1f_Wih = (const float*)d_in[11];
    const float* l1f_Whh = (const float*)d_in[12];
    const float* l1f_b   = (const float*)d_in[13];
    const float* l1b_Wih = (const float*)d_in[14];
    const float* l1b_Whh = (const float*)d_in[15];
    const float* l1b_b   = (const float*)d_in[16];
    const float* eh_W = (const float*)d_in[17];
    const float* eh_b = (const float*)d_in[18];
    const float* em_W = (const float*)d_in[19];
    const float* em_b = (const float*)d_in[20];
    const float* es_W = (const float*)d_in[21];
    const float* es_b = (const float*)d_in[22];
    const float* lh_W = (const float*)d_in[23];
    const float* lh_b = (const float*)d_in[24];
    const float* lm_W = (const float*)d_in[25];
    const float* lm_b = (const float*)d_in[26];
    const float* ls_W = (const float*)d_in[27];
    const float* ls_b = (const float*)d_in[28];

    float* out = (float*)d_out;
    float* trees_out = out;                         // 4096
    float* preds_out = out + BT;                    // 4096
    float* arc_out   = out + 2*BT;                  // 524288
    float* rel_out   = out + 2*BT + BT*N;           // 204800

    float* ws = (float*)d_ws;
    float* A       = ws;                    // 4,096,000: xg fused [m][1000]; later s3 [m][300]
    float* words   = ws + 4096000;          //   512,000
    float* C       = ws + 4608000;          // 1,024,000: h0, then ex
    float* WT_l0   = ws + 5632000;          //   125,000  [125][1000]
    float* WT_l1   = ws + 5757000;          //   250,000  [250][1000]
    float* WT_s3   = ws + 6007000;          //    75,000  [250][300]
    float* WT_lh   = ws + 6082000;          //    25,000  [250][100]
    float* WhT_l0f = ws + 6107000;          //    64,016  [128][500]+16 (pad rows zeroed)
    float* WhT_l0b = ws + 6171016;          //    64,016
    float* WhT_l1f = ws + 6235032;          //    64,016
    float* WhT_l1b = ws + 6299048;          //    64,016
    float* b_l0    = ws + 6363064;          //     1,000
    float* b_l1    = ws + 6364064;          //     1,000
    float* b_s3    = ws + 6365064;          //     1,000 (300 used)
    float* rel_head = ws + 6366064;         //   409,600  [m][100]
    // total 6,775,664 floats = 27.1 MB

    // 0. fused biases + pad-row zeroing + fused tiled transpose (12 matrices)
    bias_setup<<<9, 256, 0, stream>>>(l0f_b, l0b_b, l1f_b, l1b_b, eh_b, em_b, lm_b,
                                      b_l0, b_l1, b_s3);
    pad_zero<<<24, 256, 0, stream>>>(WhT_l0f, WhT_l0b, WhT_l1f, WhT_l1b);
    {
        TArgs ta{};
        auto tiles = [](int R, int C_) { return ((C_+31)/32) * ((R+31)/32); };
        struct { const float* s; float* d; int R, C, ldo, coff; } js[12] = {
            { l0f_Wih, WT_l0, 500, 125, 1000, 0 },
            { l0b_Wih, WT_l0, 500, 125, 1000, 500 },
            { l1f_Wih, WT_l1, 500, 250, 1000, 0 },
            { l1b_Wih, WT_l1, 500, 250, 1000, 500 },
            { eh_W, WT_s3, 100, 250, 300, 0 },
            { em_W, WT_s3, 100, 250, 300, 100 },
            { lm_W, WT_s3, 100, 250, 300, 200 },
            { lh_W, WT_lh, 100, 250, 100, 0 },
            { l0f_Whh, WhT_l0f, 500, 125, 500, 0 },
            { l0b_Whh, WhT_l0b, 500, 125, 500, 0 },
            { l1f_Whh, WhT_l1f, 500, 125, 500, 0 },
            { l1b_Whh, WhT_l1b, 500, 125, 500, 0 },
        };
        int t0 = 0;
        for (int i = 0; i < 12; i++) {
            ta.j[i].src = js[i].s;  ta.j[i].dst = js[i].d;
            ta.j[i].R = js[i].R;    ta.j[i].C = js[i].C;
            ta.j[i].ldo = js[i].ldo; ta.j[i].coff = js[i].coff;
            ta.j[i].tile0 = t0;
            ta.j[i].tiles_x = (js[i].C + 31) / 32;
            t0 += tiles(js[i].R, js[i].C);
        }
        transpose_fused<<<t0, dim3(32, 8), 0, stream>>>(ta);
    }

    // 1. embeddings
    embed_kernel<<<BT, 128, 0, stream>>>(word_ids, upos_ids, wlookup, tlookup, words);

    // 2. layer-0 input projections, fused fwd+bwd (K=125, N=1000)
    proj_t<2><<<BT/MT, 512, 0, stream>>>(words, WT_l0, b_l0, A, 1000, D, D, nullptr);

    // 3. layer-0 scan -> h0 (C)
    lstm_scan<<<B*2, 1024, 0, stream>>>(A, WhT_l0f, WhT_l0b, C);

    // 4. layer-1 input projections (K=250, N=1000)
    proj_t<2><<<BT/MT, 512, 0, stream>>>(C, WT_l1, b_l1, A, 1000, H2, H2, nullptr);

    // 5. layer-1 scan -> ex (C, overwrites h0)
    lstm_scan<<<B*2, 1024, 0, stream>>>(A, WhT_l1f, WhT_l1b, C);

    // 6. scorer projections: eh+em+lm fused (N=300) into A; lh gathered (N=100)
    proj_t<2><<<BT/MT, 192, 0, stream>>>(C, WT_s3, b_s3, A, 300, H2, H2, nullptr);
    proj_t<1><<<BT/MT, 128, 0, stream>>>(C, WT_lh, lh_b, rel_head, 100, H2, H2, target_arcs);

    // 7. arc scores + margin + argmax
    arc_kernel<<<BT/ITILE, 128, 0, stream>>>(A, es_W, es_b, target_arcs,
                                             arc_out, trees_out);

    // 8. rel scores + argmax
    rel_kernel<<<BT, 64, 0, stream>>>(A, rel_head, ls_W, ls_b, rel_out, preds_out);
}